// Round 12
// baseline (221.470 us; speedup 1.0000x reference)
//
#include <hip/hip_runtime.h>
#include <hip/hip_bf16.h>
#include <stdint.h>

// Problem constants
#define S_    2048
#define H_    2048
#define NH_   16
#define QLR_  1536
#define KVLR_ 512
#define DR_   64
#define DN_   128
#define DV_   128
#define DQK_  192            // DN + DR
#define QW_   (NH_*DQK_)     // 3072
#define KVW_  (NH_*(DN_+DV_))// 4096
#define CKVW_ (KVLR_+DR_)    // 576

typedef __attribute__((ext_vector_type(8))) short short8;
typedef __attribute__((ext_vector_type(4))) float floatx4;

__device__ __forceinline__ unsigned short f2bf(float f) {
    unsigned u = __float_as_uint(f);
    unsigned r = u + 0x7fffu + ((u >> 16) & 1u);
    return (unsigned short)(r >> 16);
}
__device__ __forceinline__ float bf2f(unsigned short h) {
    return __uint_as_float(((unsigned)h) << 16);
}
__device__ __forceinline__ void store_out(float* p, float v) { *p = v; }
__device__ __forceinline__ void store_out(unsigned short* p, float v) { *p = f2bf(v); }

// async global->LDS, 16 bytes per lane (lane-linear dest)
typedef const __attribute__((address_space(1))) unsigned int* gas_ptr;
typedef __attribute__((address_space(3))) unsigned int* las_ptr;
__device__ __forceinline__ void gload16(const void* g, void* l) {
    __builtin_amdgcn_global_load_lds((gas_ptr)g, (las_ptr)l, 16, 0, 0);
}

// bijective XCD-aware swizzle (m204): orig linear wg -> swizzled wg
__device__ __forceinline__ int xcd_swz(int orig, int nwg) {
    int q8 = nwg >> 3, r8 = nwg & 7;
    int xcd = orig & 7, jj = orig >> 3;
    return (xcd < r8 ? xcd * (q8 + 1) : r8 * (q8 + 1) + (xcd - r8) * q8) + jj;
}

// ---------------------------------------------------------------------------
// bf16 MFMA GEMM, double-buffered, 64x128 tile, BK=64 (round-6/9 verified).
// BK=64 stored as TWO BK=32 sub-tiles per buffer (64B row stride, no bank
// conflicts). C[M,N] = A[M,K] @ Bt[N,K]^T. 4 waves (2x2), 2x4 frags/wave.
// M%64==0, K%64==0, N arbitrary (clamped loads, guarded stores).
// ---------------------------------------------------------------------------
#define GEMM_STAGE(b, k0) do {                                               \
        _Pragma("unroll")                                                    \
        for (int sub = 0; sub < 2; ++sub) {                                  \
            int m = tid >> 2, k8 = tid & 3;                                  \
            gload16(A + (size_t)(bm + m) * lda + (k0) + sub * 32 + k8 * 8,   \
                    &As[b][sub][tid * 8]);                                   \
        }                                                                    \
        _Pragma("unroll")                                                    \
        for (int sub = 0; sub < 2; ++sub)                                    \
            _Pragma("unroll")                                                \
            for (int j = 0; j < BN / 64; ++j) {                              \
                int ch = j * 256 + tid;                                      \
                int n = ch >> 2, k8 = ch & 3;                                \
                int nrow = bn + n; if (nrow >= N) nrow = N - 1;              \
                gload16(Bt + (size_t)nrow * K + (k0) + sub * 32 + k8 * 8,    \
                        &Bs[b][sub][ch * 8]);                                \
            }                                                                \
    } while (0)

#define GEMM_COMPUTE_SUB(sub) do {                                           \
        short8 a[2], b[NFR];                                                 \
        _Pragma("unroll")                                                    \
        for (int mi = 0; mi < 2; ++mi)                                       \
            a[mi] = *(const short8*)&As[cur][sub][(wm + mi * 16 + cc) * 32 + g * 8]; \
        _Pragma("unroll")                                                    \
        for (int ni = 0; ni < NFR; ++ni)                                     \
            b[ni] = *(const short8*)&Bs[cur][sub][(wn + ni * 16 + cc) * 32 + g * 8]; \
        __builtin_amdgcn_s_setprio(1);                                       \
        _Pragma("unroll")                                                    \
        for (int mi = 0; mi < 2; ++mi)                                       \
            _Pragma("unroll")                                                \
            for (int ni = 0; ni < NFR; ++ni)                                 \
                acc[mi][ni] = __builtin_amdgcn_mfma_f32_16x16x32_bf16(       \
                    a[mi], b[ni], acc[mi][ni], 0, 0, 0);                     \
        __builtin_amdgcn_s_setprio(0);                                       \
    } while (0)

template <typename OutT, int BN>
__global__ __launch_bounds__(256) void gemm_bf16_db(
    const unsigned short* __restrict__ A, const unsigned short* __restrict__ Bt,
    OutT* __restrict__ C, int M, int N, int K, int lda, int ldc)
{
    constexpr int NFR = BN / 32;
    __shared__ unsigned short As[2][2][64 * 32];
    __shared__ unsigned short Bs[2][2][BN * 32];

    const int tid = threadIdx.x;
    const int l = tid & 63;
    const int g = l >> 4, cc = l & 15;
    const int w = tid >> 6;
    const int wm = (w >> 1) * 32, wn = (w & 1) * (BN / 2);

    const int nwg = gridDim.x * gridDim.y;
    const int wg = xcd_swz(blockIdx.y * gridDim.x + blockIdx.x, nwg);
    const int bm = (wg / gridDim.x) * 64;
    const int bn = (wg % gridDim.x) * BN;

    floatx4 acc[2][NFR];
#pragma unroll
    for (int i = 0; i < 2; i++)
#pragma unroll
        for (int j = 0; j < NFR; j++) acc[i][j] = (floatx4){0.f, 0.f, 0.f, 0.f};

    GEMM_STAGE(0, 0);
    __syncthreads();
    int cur = 0;

    for (int k0 = 0; k0 < K; k0 += 64) {
        if (k0 + 64 < K) GEMM_STAGE(cur ^ 1, k0 + 64);
        GEMM_COMPUTE_SUB(0);
        GEMM_COMPUTE_SUB(1);
        __syncthreads();
        cur ^= 1;
    }

#pragma unroll
    for (int mi = 0; mi < 2; ++mi)
#pragma unroll
        for (int ni = 0; ni < NFR; ++ni)
#pragma unroll
            for (int i = 0; i < 4; ++i) {
                int row = bm + wm + mi * 16 + g * 4 + i;
                int col = bn + wn + ni * 16 + cc;
                if (col < N) store_out(&C[(size_t)row * ldc + col], acc[mi][ni][i]);
            }
}

// Dual-output variant for the fused q_a|kv_a projection (64x128, BK=64).
__global__ __launch_bounds__(256) void gemm_bf16_dual(
    const unsigned short* __restrict__ A, const unsigned short* __restrict__ Bt,
    float* __restrict__ C0, float* __restrict__ C1,
    int M, int N, int K, int lda, int ldc0, int ldc1)
{
    constexpr int BN = 128;
    constexpr int NFR = 4;
    __shared__ unsigned short As[2][2][64 * 32];
    __shared__ unsigned short Bs[2][2][BN * 32];

    const int tid = threadIdx.x;
    const int l = tid & 63;
    const int g = l >> 4, cc = l & 15;
    const int w = tid >> 6;
    const int wm = (w >> 1) * 32, wn = (w & 1) * (BN / 2);

    const int nwg = gridDim.x * gridDim.y;
    const int wg = xcd_swz(blockIdx.y * gridDim.x + blockIdx.x, nwg);
    const int bm = (wg / gridDim.x) * 64;
    const int bn = (wg % gridDim.x) * BN;

    floatx4 acc[2][NFR];
#pragma unroll
    for (int i = 0; i < 2; i++)
#pragma unroll
        for (int j = 0; j < NFR; j++) acc[i][j] = (floatx4){0.f, 0.f, 0.f, 0.f};

    GEMM_STAGE(0, 0);
    __syncthreads();
    int cur = 0;

    for (int k0 = 0; k0 < K; k0 += 64) {
        if (k0 + 64 < K) GEMM_STAGE(cur ^ 1, k0 + 64);
        GEMM_COMPUTE_SUB(0);
        GEMM_COMPUTE_SUB(1);
        __syncthreads();
        cur ^= 1;
    }

#pragma unroll
    for (int mi = 0; mi < 2; ++mi)
#pragma unroll
        for (int ni = 0; ni < NFR; ++ni)
#pragma unroll
            for (int i = 0; i < 4; ++i) {
                int row = bm + wm + mi * 16 + g * 4 + i;
                int col = bn + wn + ni * 16 + cc;
                if (col < QLR_)
                    C0[(size_t)row * ldc0 + col] = acc[mi][ni][i];
                else if (col < N)
                    C1[(size_t)row * ldc1 + (col - QLR_)] = acc[mi][ni][i];
            }
}

// ---------------------------------------------------------------------------
// Paired GEMM (round-10 verified): q_b and kv_b in ONE launch. Blocks
// [0,nwg0) run GEMM0, [nwg0,nwg0+nwg1) run GEMM1.
// ---------------------------------------------------------------------------
__global__ __launch_bounds__(256) void gemm_bf16_pair(
    const unsigned short* __restrict__ A0, const unsigned short* __restrict__ Bt0,
    unsigned short* __restrict__ Cp0, int N0, int K0, int lda0, int ldc0, int gx0, int nwg0,
    const unsigned short* __restrict__ A1, const unsigned short* __restrict__ Bt1,
    unsigned short* __restrict__ Cp1, int N1, int K1, int lda1, int ldc1, int gx1, int nwg1)
{
    constexpr int BN = 128;
    constexpr int NFR = 4;
    __shared__ unsigned short As[2][2][64 * 32];
    __shared__ unsigned short Bs[2][2][BN * 32];

    const int tid = threadIdx.x;
    const int l = tid & 63;
    const int g = l >> 4, cc = l & 15;
    const int w = tid >> 6;
    const int wm = (w >> 1) * 32, wn = (w & 1) * (BN / 2);

    const int bid = blockIdx.x;
    const unsigned short *A, *Bt;
    unsigned short* C;
    int N, K, lda, ldc, wg, gx;
    if (bid < nwg0) {
        wg = xcd_swz(bid, nwg0); gx = gx0;
        A = A0; Bt = Bt0; C = Cp0; N = N0; K = K0; lda = lda0; ldc = ldc0;
    } else {
        wg = xcd_swz(bid - nwg0, nwg1); gx = gx1;
        A = A1; Bt = Bt1; C = Cp1; N = N1; K = K1; lda = lda1; ldc = ldc1;
    }
    const int bm = (wg / gx) * 64;
    const int bn = (wg % gx) * BN;

    floatx4 acc[2][NFR];
#pragma unroll
    for (int i = 0; i < 2; i++)
#pragma unroll
        for (int j = 0; j < NFR; j++) acc[i][j] = (floatx4){0.f, 0.f, 0.f, 0.f};

    GEMM_STAGE(0, 0);
    __syncthreads();
    int cur = 0;

    for (int k0 = 0; k0 < K; k0 += 64) {
        if (k0 + 64 < K) GEMM_STAGE(cur ^ 1, k0 + 64);
        GEMM_COMPUTE_SUB(0);
        GEMM_COMPUTE_SUB(1);
        __syncthreads();
        cur ^= 1;
    }

#pragma unroll
    for (int mi = 0; mi < 2; ++mi)
#pragma unroll
        for (int ni = 0; ni < NFR; ++ni)
#pragma unroll
            for (int i = 0; i < 4; ++i) {
                int row = bm + wm + mi * 16 + g * 4 + i;
                int col = bn + wn + ni * 16 + cc;
                if (col < N) C[(size_t)row * ldc + col] = f2bf(acc[mi][ni][i]);
            }
}

__global__ __launch_bounds__(256) void cast_bf16(
    const float* __restrict__ in, unsigned short* __restrict__ out, int n)
{
    int i = (blockIdx.x * 256 + threadIdx.x) * 4;
    if (i >= n) return;
    float4 v = *(const float4*)&in[i];
    ushort4 u;
    u.x = f2bf(v.x); u.y = f2bf(v.y); u.z = f2bf(v.z); u.w = f2bf(v.w);
    *(ushort4*)&out[i] = u;
}

__global__ __launch_bounds__(256) void transpose_cast(
    const float* __restrict__ W, unsigned short* __restrict__ Wt, int K, int N,
    float scl)
{
    __shared__ float t[32][33];
    const int n0 = blockIdx.x * 32, k0 = blockIdx.y * 32;
    const int tx = threadIdx.x & 31, ty4 = (threadIdx.x >> 5) * 4;
#pragma unroll
    for (int j = 0; j < 4; ++j)
        t[ty4 + j][tx] = W[(size_t)(k0 + ty4 + j) * N + n0 + tx];
    __syncthreads();
#pragma unroll
    for (int j = 0; j < 4; ++j)
        Wt[(size_t)(n0 + ty4 + j) * K + k0 + tx] = f2bf(t[tx][ty4 + j] * scl);
}

__global__ __launch_bounds__(256) void rmsnorm_bf16out(
    const float* __restrict__ x, const float* __restrict__ w,
    unsigned short* __restrict__ y, int cols, int xstride)
{
    const float* xr = x + (size_t)blockIdx.x * xstride;
    unsigned short* yr = y + (size_t)blockIdx.x * cols;
    const int tid = threadIdx.x;
    float ss = 0.f;
    for (int c = tid; c < cols; c += 256) { float v = xr[c]; ss += v * v; }
#pragma unroll
    for (int off = 32; off > 0; off >>= 1) ss += __shfl_xor(ss, off);
    __shared__ float red[4];
    if ((tid & 63) == 0) red[tid >> 6] = ss;
    __syncthreads();
    ss = red[0] + red[1] + red[2] + red[3];
    const float inv = rsqrtf(ss / (float)cols + 1e-6f);
    for (int c = tid; c < cols; c += 256) yr[c] = f2bf(xr[c] * inv * w[c]);
}

// Interleaved RoPE in place on bf16 q rot slices.
__global__ void rope_q_bf(unsigned short* __restrict__ q,
                          const float* __restrict__ cs, const float* __restrict__ sn)
{
    int t = blockIdx.x * 256 + threadIdx.x;
    int chunk = t >> 5, j = t & 31;
    int s = chunk >> 4, h = chunk & 15;
    unsigned short* x = q + (size_t)s * QW_ + h * DQK_ + DN_;
    float e = bf2f(x[2 * j]), o = bf2f(x[2 * j + 1]);
    float c = cs[s * DR_ + j], si = sn[s * DR_ + j];
    unsigned short u = f2bf(e * c - o * si);
    unsigned short v = f2bf(o * c + e * si);
    x[j] = u; x[j + 32] = v;
}

// ---------------------------------------------------------------------------
// prep_k: kg[h][s][192] bf16 = [k_pass(h) | rope(k_rot)], 16B-chunk XOR
// swizzle (chunk d8 stored at d8 ^ (s&7)) baked in (rule-21 pattern).
// ---------------------------------------------------------------------------
__global__ __launch_bounds__(256) void prep_k(
    const unsigned short* __restrict__ kvb, const float* __restrict__ ckv,
    const float* __restrict__ cs, const float* __restrict__ sn,
    unsigned short* __restrict__ kg)
{
    const int s = blockIdx.x, tid = threadIdx.x;
    __shared__ unsigned short rot[64];
    if (tid < 32) {
        int j = tid;
        const float* x = ckv + (size_t)s * CKVW_ + KVLR_;
        float e = x[2 * j], o = x[2 * j + 1];
        float c = cs[s * DR_ + j], si = sn[s * DR_ + j];
        rot[j] = f2bf(e * c - o * si);
        rot[j + 32] = f2bf(o * c + e * si);
    }
    __syncthreads();
    const int sw = s & 7;
    for (int ch = tid; ch < 384; ch += 256) {
        int hh = ch / 24, d8 = ch % 24;
        short8 v;
        if (d8 < 16)
            v = *(const short8*)&kvb[(size_t)s * KVW_ + hh * 256 + d8 * 8];
        else
            v = *(const short8*)&rot[(d8 - 16) * 8];
        int d8s = d8 ^ sw;
        *(short8*)&kg[((size_t)hh * S_ + s) * 192 + d8s * 8] = v;
    }
}

// ---------------------------------------------------------------------------
// transpose_v: vt[h*128+dv][s] <- kvb[s][h*256+128+dv]
// ---------------------------------------------------------------------------
__global__ __launch_bounds__(256) void transpose_v(
    const unsigned short* __restrict__ kvb, unsigned short* __restrict__ vt)
{
    __shared__ unsigned short t[32][36];
    const int dv0 = blockIdx.x * 32, s0 = blockIdx.y * 32, h = blockIdx.z;
    const int r = threadIdx.x >> 3, c4 = threadIdx.x & 7;
    ushort4 ld = *(const ushort4*)&kvb[(size_t)(s0 + r) * KVW_ + h * 256 + 128 + dv0 + c4 * 4];
    t[r][c4 * 4 + 0] = ld.x; t[r][c4 * 4 + 1] = ld.y;
    t[r][c4 * 4 + 2] = ld.z; t[r][c4 * 4 + 3] = ld.w;
    __syncthreads();
    ushort4 st;
    st.x = t[c4 * 4 + 0][r]; st.y = t[c4 * 4 + 1][r];
    st.z = t[c4 * 4 + 2][r]; st.w = t[c4 * 4 + 3][r];
    *(ushort4*)&vt[(size_t)(h * 128 + dv0 + r) * S_ + s0 + c4 * 4] = st;
}

// ---------------------------------------------------------------------------
// Flash attention v11 (round-11): the verified v7 body (QBLK=64, 4 waves,
// 2-way block kv-split) with the P LDS ROUND-TRIP REPLACED by an 8-shuffle
// in-register distribution:
//   lane (g,cc) owns cvt_pk words pk00/pk01 (kv=4g..4g+3) and pk10/pk11
//   (kv=16+4g..16+4g+3); the PV A-fragment needs P[q=cc][kv=8g..8g+7] =
//   4 packed words from lanes (2(g&1))<<4|cc and that +16, pk0x if g<2
//   else pk1x. Removes 2 ds_write + 1 ds_read + lgkm wait per iteration.
// LDS drops to 40 KB -> 4 blocks/CU (16 waves). Log2 softmax, T13
// defer-rescale, cvt_pk pack. Emits UNNORMALIZED partial O + (m,l).
// ---------------------------------------------------------------------------
__global__ __launch_bounds__(256, 4) void flash_attn7(
    const unsigned short* __restrict__ qg, const unsigned short* __restrict__ kg,
    const unsigned short* __restrict__ vt,
    unsigned short* __restrict__ op0, unsigned short* __restrict__ op1,
    float* __restrict__ mlp)
{
    const int bid = blockIdx.x;
    const int qblk = 31 - (bid >> 5);    // LPT: longest q-blocks first
    const int low5 = bid & 31;
    const int h = low5 & 15;             // bid&7 = h&7 -> head pinned to XCD
    const int sp = low5 >> 4;            // kv-split half
    const int pb = h * 32 + qblk;        // partial-buffer index

    // LDS: K[2][6144 us] + V[2][4096 us] = 20480 us = 40 KB (no P buffer)
    __shared__ unsigned short sm[2 * 6144 + 2 * 4096];
    unsigned short* Kb = sm;                     // [2][32 k][192 d] (XOR-swz)
    unsigned short* Vb = sm + 12288;             // [2][128 dv][32 k]
    const int tid = threadIdx.x;
    const int w = tid >> 6;              // 0..3 : q-strip
    const int l = tid & 63, g = l >> 4, cc = l & 15;

    const int qmin = qblk * 64 + w * 16;
    const int q_lane = qmin + cc;        // this lane's q row
    const int wave_qmax = qmin + 15;
    const int HT = qblk + 1;             // tiles per split half
    const int kt_begin = sp * HT, kt_end = kt_begin + HT;

    const unsigned short* kh = kg + (size_t)h * S_ * 192;
    const unsigned short* vh = vt + (size_t)(h * 128) * S_;

    // Q fragments direct from global (once per block; small tx count)
    short8 qf[6];
    {
        const unsigned short* qb = qg + (size_t)q_lane * QW_ + h * DQK_;
#pragma unroll
        for (int k6 = 0; k6 < 6; ++k6)
            qf[k6] = *(const short8*)&qb[k6 * 32 + g * 8];
    }

    floatx4 accO[8];
#pragma unroll
    for (int nt = 0; nt < 8; ++nt) accO[nt] = (floatx4){0.f, 0.f, 0.f, 0.f};
    float m_r = -1e30f, l_r = 0.f;   // q-row = cc (replicated across g), log2 domain

    // coalesced K+V tile staging (kg pre-swizzled globally -> linear copy)
#define STAGE_KV(b, kt) do {                                             \
        const unsigned short* ksrc = kh + (size_t)(kt) * 32 * 192;       \
        _Pragma("unroll")                                                \
        for (int j = 0; j < 3; ++j) {                                    \
            int ch = j * 256 + tid;                                      \
            gload16(ksrc + ch * 8, Kb + (b) * 6144 + ch * 8);            \
        }                                                                \
        const int krow = (kt) * 32;                                      \
        _Pragma("unroll")                                                \
        for (int j = 0; j < 2; ++j) {                                    \
            int ch = j * 256 + tid;                                      \
            int dv = ch >> 2, j8 = ch & 3;                               \
            gload16(vh + (size_t)dv * S_ + krow + j8 * 8,                \
                    Vb + (b) * 4096 + ch * 8);                           \
        }                                                                \
    } while (0)

    STAGE_KV(0, kt_begin);
    int cur = 0;

    // wave-uniform loop bounds; per-wave guard inside
    for (int kt = kt_begin; kt < kt_end; ++kt) {
        const int krow0 = kt * 32;
        __syncthreads();   // staged data for kt ready (barrier drains vmcnt)
        if (kt + 1 < kt_end) STAGE_KV(cur ^ 1, kt + 1);

        if (krow0 <= wave_qmax) {
            const unsigned short* Kc = Kb + cur * 6144;
            const unsigned short* Vc = Vb + cur * 4096;
            const int swz = (cc & 7) << 3;

            floatx4 s0 = (floatx4){0.f, 0.f, 0.f, 0.f};
            floatx4 s1 = (floatx4){0.f, 0.f, 0.f, 0.f};
            __builtin_amdgcn_s_setprio(1);
#pragma unroll
            for (int k6 = 0; k6 < 6; ++k6) {
                short8 b0 = *(const short8*)&Kc[cc * 192 + ((k6 * 32 + g * 8) ^ swz)];
                short8 b1 = *(const short8*)&Kc[(16 + cc) * 192 + ((k6 * 32 + g * 8) ^ swz)];
                // SWAPPED: A = K rows, B = Q rows -> D[kv][q]
                s0 = __builtin_amdgcn_mfma_f32_16x16x32_bf16(b0, qf[k6], s0, 0, 0, 0);
                s1 = __builtin_amdgcn_mfma_f32_16x16x32_bf16(b1, qf[k6], s1, 0, 0, 0);
            }
            __builtin_amdgcn_s_setprio(0);

            // scores for q=cc (log2 domain; scale folded into wq_b)
            float v0[4], v1[4];
            if (krow0 + 31 <= qmin) {
#pragma unroll
                for (int i = 0; i < 4; ++i) { v0[i] = s0[i]; v1[i] = s1[i]; }
            } else {
#pragma unroll
                for (int i = 0; i < 4; ++i) {
                    v0[i] = (krow0 + g * 4 + i) <= q_lane ? s0[i] : -1e30f;
                    v1[i] = (krow0 + 16 + g * 4 + i) <= q_lane ? s1[i] : -1e30f;
                }
            }
            float mt = fmaxf(fmaxf(fmaxf(v0[0], v0[1]), fmaxf(v0[2], v0[3])),
                             fmaxf(fmaxf(v1[0], v1[1]), fmaxf(v1[2], v1[3])));
            mt = fmaxf(mt, __shfl_xor(mt, 16));
            mt = fmaxf(mt, __shfl_xor(mt, 32));

            // T13 defer-rescale: wave-uniform skip when max grows < 6 (log2)
            if (!__all(mt <= m_r + 6.0f)) {
                float mn = fmaxf(m_r, mt);
                float alpha = exp2f(m_r - mn);
                m_r = mn;
                l_r *= alpha;
                float aB[4];
#pragma unroll
                for (int i = 0; i < 4; ++i) aB[i] = __shfl(alpha, g * 4 + i);
#pragma unroll
                for (int nt = 0; nt < 8; ++nt)
#pragma unroll
                    for (int i = 0; i < 4; ++i) accO[nt][i] *= aB[i];
            }

            float p0[4], p1[4], ps = 0.f;
#pragma unroll
            for (int i = 0; i < 4; ++i) {
                p0[i] = exp2f(v0[i] - m_r);   // masked lanes: exp2(-huge) = 0
                p1[i] = exp2f(v1[i] - m_r);
                ps += p0[i] + p1[i];
            }
            ps += __shfl_xor(ps, 16);
            ps += __shfl_xor(ps, 32);
            l_r += ps;

            // pack P to bf16 pairs (HW cvt_pk) and distribute the PV
            // A-fragment fully in-register (8 shuffles, no LDS round-trip)
            short8 pf;
            {
                unsigned pk00, pk01, pk10, pk11;
                asm("v_cvt_pk_bf16_f32 %0, %1, %2" : "=v"(pk00) : "v"(p0[0]), "v"(p0[1]));
                asm("v_cvt_pk_bf16_f32 %0, %1, %2" : "=v"(pk01) : "v"(p0[2]), "v"(p0[3]));
                asm("v_cvt_pk_bf16_f32 %0, %1, %2" : "=v"(pk10) : "v"(p1[0]), "v"(p1[1]));
                asm("v_cvt_pk_bf16_f32 %0, %1, %2" : "=v"(pk11) : "v"(p1[2]), "v"(p1[3]));
                const int lA = ((g & 1) << 5) | cc;   // lane of src g = 2*(g&1)
                const int lB = lA | 16;               // src g + 1
                unsigned a0 = __shfl((int)pk00, lA), a1 = __shfl((int)pk01, lA);
                unsigned b0 = __shfl((int)pk00, lB), b1 = __shfl((int)pk01, lB);
                unsigned c0 = __shfl((int)pk10, lA), c1 = __shfl((int)pk11, lA);
                unsigned d0 = __shfl((int)pk10, lB), d1 = __shfl((int)pk11, lB);
                const bool lo = g < 2;
                uint4 pw;
                pw.x = lo ? a0 : c0;
                pw.y = lo ? a1 : c1;
                pw.z = lo ? b0 : d0;
                pw.w = lo ? b1 : d1;
                pf = *(short8*)&pw;
            }

            __builtin_amdgcn_s_setprio(1);
#pragma unroll
            for (int nt = 0; nt < 8; ++nt) {
                short8 vr = *(const short8*)&Vc[(nt * 16 + cc) * 32 + g * 8];
                accO[nt] = __builtin_amdgcn_mfma_f32_16x16x32_bf16(pf, vr, accO[nt], 0, 0, 0);
            }
            __builtin_amdgcn_s_setprio(0);
        }
        cur ^= 1;
    }
#undef STAGE_KV

    // ---- emit unnormalized partial + (m,l) ----
    float mB[4], lB4[4];
#pragma unroll
    for (int i = 0; i < 4; ++i) {
        int src = (g << 4) | (g * 4 + i);   // lane with cc == g*4+i (same g)
        mB[i] = __shfl(m_r, src);
        lB4[i] = __shfl(l_r, src);
    }
    unsigned short* op = sp ? op1 : op0;
#pragma unroll
    for (int nt = 0; nt < 8; ++nt)
#pragma unroll
        for (int i = 0; i < 4; ++i)
            op[(size_t)pb * 8192 + (w * 16 + g * 4 + i) * 128 + nt * 16 + cc] =
                f2bf(accO[nt][i]);
    if (cc == 0) {
#pragma unroll
        for (int i = 0; i < 4; ++i) {
            size_t mi = ((size_t)(sp * 512 + pb) * 64 + w * 16 + g * 4 + i) * 2;
            mlp[mi + 0] = mB[i];
            mlp[mi + 1] = lB4[i];
        }
    }
}

// ---------------------------------------------------------------------------
// merge_attn: combine the two kv-split partials per (h,qblk) -> ao bf16.
// grid 512 blocks x 256 threads; thread = (row = tid>>2, 32-col segment).
// ---------------------------------------------------------------------------
__global__ __launch_bounds__(256) void merge_attn(
    const unsigned short* __restrict__ op0, const unsigned short* __restrict__ op1,
    const float* __restrict__ mlp, unsigned short* __restrict__ ao)
{
    const int pb = blockIdx.x;           // h*32 + qblk
    const int h = pb >> 5, qblk = pb & 31;
    const int tid = threadIdx.x;
    const int row = tid >> 2, c0 = (tid & 3) * 32;

    const size_t mi0 = ((size_t)pb * 64 + row) * 2;
    const size_t mi1 = ((size_t)(512 + pb) * 64 + row) * 2;
    float m0 = mlp[mi0 + 0], l0 = mlp[mi0 + 1];
    float m1 = mlp[mi1 + 0], l1 = mlp[mi1 + 1];
    float mf = fmaxf(m0, m1);
    float e0 = exp2f(m0 - mf), e1 = exp2f(m1 - mf);
    float inv = 1.f / (l0 * e0 + l1 * e1);
    float w0 = e0 * inv, w1 = e1 * inv;

    const size_t pbase = (size_t)pb * 8192 + row * 128 + c0;
    unsigned short* dst = ao + (size_t)(qblk * 64 + row) * (NH_ * DV_) + h * DV_ + c0;
#pragma unroll
    for (int j = 0; j < 4; ++j) {
        short8 a = *(const short8*)&op0[pbase + j * 8];
        short8 b = *(const short8*)&op1[pbase + j * 8];
        short8 o;
#pragma unroll
        for (int k = 0; k < 8; ++k)
            o[k] = (short)f2bf(bf2f((unsigned short)a[k]) * w0 +
                               bf2f((unsigned short)b[k]) * w1);
        *(short8*)&dst[j * 8] = o;
    }
}

// ---------------------------------------------------------------------------
extern "C" void kernel_launch(void* const* d_in, const int* in_sizes, int n_in,
                              void* d_out, int out_size, void* d_ws, size_t ws_size,
                              hipStream_t stream)
{
    const float* hs    = (const float*)d_in[0];
    const float* cosp  = (const float*)d_in[1];
    const float* sinp  = (const float*)d_in[2];
    const float* wq_a  = (const float*)d_in[3];
    const float* q_ln  = (const float*)d_in[4];
    const float* wq_b  = (const float*)d_in[5];
    const float* wkv_a = (const float*)d_in[6];
    const float* kv_ln = (const float*)d_in[7];
    const float* wkv_b = (const float*)d_in[8];
    const float* wo    = (const float*)d_in[9];
    float* out = (float*)d_out;

    char* ws = (char*)d_ws;
    float*          qa     = (float*)(ws);                        // [2048][1536] f32 (dead after rms -> wbt2/kg)
    float*          ckv    = (float*)(ws + 12582912);             // [2048][576]  f32 (dead after prep_k -> mlp)
    unsigned short* q_bf   = (unsigned short*)(ws + 17301504);    // [2048][3072] bf16
    unsigned short* kvb    = (unsigned short*)(ws + 29884416);    // [2048][4096] bf16
    unsigned short* hs_bf  = (unsigned short*)(ws + 46661632);    // [2048][2048] bf16 (dead after fused gemm -> vtb)
    unsigned short* qa_bf  = (unsigned short*)(ws + 55050240);    // [2048][1536] bf16 (dead after q_b gemm -> op0)
    unsigned short* ckv_bf = (unsigned short*)(ws + 61341696);    // [2048][512]  bf16
    unsigned short* ao_bf  = (unsigned short*)(ws + 63438848);    // [2048][2048] bf16
    unsigned short* wt     = (unsigned short*)(ws + 71827456);    // [3072][1536] bf16 max (dead during flash -> op1)
    unsigned short* kg     = (unsigned short*)qa;                 // [16][2048][192] bf16
    unsigned short* vtb    = hs_bf;                               // [16*128][2048] bf16
    unsigned short* wbt2   = (unsigned short*)qa;                 // [4096][512] bf16 (wkv_b^T; qa dead, kg written later)

    // flash partials (alias dead regions during attention):
    unsigned short* op0 = qa_bf;                       // 512*8192 bf16 = 8.39 MB
    unsigned short* op1 = wt;                          // 512*8192 bf16 = 8.39 MB
    float*          mlp = ckv;                         // 2*512*64*2 f32 = 0.5 MB

    // scores scale * log2(e), folded into wq_b (q only feeds QK^T; RoPE linear)
    const float qscale = 0.07216878364870322f * 1.4426950408889634f;

    // hs -> bf16
    cast_bf16<<<(S_ * H_) / 1024, 256, 0, stream>>>(hs, hs_bf, S_ * H_);

    // fused q_a|kv_a projection: Bt = [wq_a^T (1536 rows) | wkv_a^T (576 rows)]
    transpose_cast<<<dim3(QLR_ / 32, H_ / 32), 256, 0, stream>>>(wq_a, wt, H_, QLR_, 1.f);
    transpose_cast<<<dim3(CKVW_ / 32, H_ / 32), 256, 0, stream>>>(
        wkv_a, wt + (size_t)QLR_ * H_, H_, CKVW_, 1.f);
    gemm_bf16_dual<<<dim3((QLR_ + CKVW_ + 127) / 128, S_ / 64), 256, 0, stream>>>(
        hs_bf, wt, qa, ckv, S_, QLR_ + CKVW_, H_, H_, QLR_, CKVW_);
    rmsnorm_bf16out<<<S_, 256, 0, stream>>>(qa, q_ln, qa_bf, QLR_, QLR_);
    rmsnorm_bf16out<<<S_, 256, 0, stream>>>(ckv, kv_ln, ckv_bf, KVLR_, CKVW_);

    // q_b + kv_b in ONE launch (round-10): wq_b^T -> wt, wkv_b^T -> wbt2
    transpose_cast<<<dim3(QW_ / 32, QLR_ / 32), 256, 0, stream>>>(wq_b, wt, QLR_, QW_, qscale);
    transpose_cast<<<dim3(KVW_ / 32, KVLR_ / 32), 256, 0, stream>>>(wkv_b, wbt2, KVLR_, KVW_, 1.f);
    gemm_bf16_pair<<<768 + 1024, 256, 0, stream>>>(
        qa_bf, wt, q_bf, QW_, QLR_, QLR_, QW_, QW_ / 128, 768,
        ckv_bf, wbt2, kvb, KVW_, KVLR_, KVLR_, KVW_, KVW_ / 128, 1024);
    rope_q_bf<<<(S_ * NH_ * 32) / 256, 256, 0, stream>>>(q_bf, cosp, sinp);

    // build kg (swizzled, rope fused; overwrites wbt2) and vt
    prep_k<<<S_, 256, 0, stream>>>(kvb, ckv, cosp, sinp, kg);
    transpose_v<<<dim3(4, 64, 16), 256, 0, stream>>>(kvb, vtb);

    // attention: QBLK=64, in-register P distribution, 4 blocks/CU
    flash_attn7<<<1024, 256, 0, stream>>>(q_bf, kg, vtb, op0, op1, mlp);
    merge_attn<<<512, 256, 0, stream>>>(op0, op1, mlp, ao_bf);

    // output projection (wt reused AFTER merge has consumed op1)
    transpose_cast<<<dim3(H_ / 32, H_ / 32), 256, 0, stream>>>(wo, wt, H_, H_, 1.f);
    gemm_bf16_db<float, 128><<<dim3(H_ / 128, S_ / 64), 256, 0, stream>>>(
        ao_bf, wt, out, S_, H_, NH_ * DV_, NH_ * DV_, H_);
}

// Round 13
// 214.163 us; speedup vs baseline: 1.0341x; 1.0341x over previous
//
#include <hip/hip_runtime.h>
#include <hip/hip_bf16.h>
#include <stdint.h>

// Problem constants
#define S_    2048
#define H_    2048
#define NH_   16
#define QLR_  1536
#define KVLR_ 512
#define DR_   64
#define DN_   128
#define DV_   128
#define DQK_  192            // DN + DR
#define QW_   (NH_*DQK_)     // 3072
#define KVW_  (NH_*(DN_+DV_))// 4096
#define CKVW_ (KVLR_+DR_)    // 576

typedef __attribute__((ext_vector_type(8))) short short8;
typedef __attribute__((ext_vector_type(4))) float floatx4;

__device__ __forceinline__ unsigned short f2bf(float f) {
    unsigned u = __float_as_uint(f);
    unsigned r = u + 0x7fffu + ((u >> 16) & 1u);
    return (unsigned short)(r >> 16);
}
__device__ __forceinline__ float bf2f(unsigned short h) {
    return __uint_as_float(((unsigned)h) << 16);
}
__device__ __forceinline__ void store_out(float* p, float v) { *p = v; }
__device__ __forceinline__ void store_out(unsigned short* p, float v) { *p = f2bf(v); }

// async global->LDS, 16 bytes per lane (lane-linear dest)
typedef const __attribute__((address_space(1))) unsigned int* gas_ptr;
typedef __attribute__((address_space(3))) unsigned int* las_ptr;
__device__ __forceinline__ void gload16(const void* g, void* l) {
    __builtin_amdgcn_global_load_lds((gas_ptr)g, (las_ptr)l, 16, 0, 0);
}

// bijective XCD-aware swizzle (m204): orig linear wg -> swizzled wg
__device__ __forceinline__ int xcd_swz(int orig, int nwg) {
    int q8 = nwg >> 3, r8 = nwg & 7;
    int xcd = orig & 7, jj = orig >> 3;
    return (xcd < r8 ? xcd * (q8 + 1) : r8 * (q8 + 1) + (xcd - r8) * q8) + jj;
}

// ---------------------------------------------------------------------------
// bf16 MFMA GEMM, double-buffered, 64x128 tile, BK=64 (round-6/9 verified).
// BK=64 stored as TWO BK=32 sub-tiles per buffer (64B row stride, no bank
// conflicts). C[M,N] = A[M,K] @ Bt[N,K]^T. 4 waves (2x2), 2x4 frags/wave.
// M%64==0, K%64==0, N arbitrary (clamped loads, guarded stores).
// ---------------------------------------------------------------------------
#define GEMM_STAGE(b, k0) do {                                               \
        _Pragma("unroll")                                                    \
        for (int sub = 0; sub < 2; ++sub) {                                  \
            int m = tid >> 2, k8 = tid & 3;                                  \
            gload16(A + (size_t)(bm + m) * lda + (k0) + sub * 32 + k8 * 8,   \
                    &As[b][sub][tid * 8]);                                   \
        }                                                                    \
        _Pragma("unroll")                                                    \
        for (int sub = 0; sub < 2; ++sub)                                    \
            _Pragma("unroll")                                                \
            for (int j = 0; j < BN / 64; ++j) {                              \
                int ch = j * 256 + tid;                                      \
                int n = ch >> 2, k8 = ch & 3;                                \
                int nrow = bn + n; if (nrow >= N) nrow = N - 1;              \
                gload16(Bt + (size_t)nrow * K + (k0) + sub * 32 + k8 * 8,    \
                        &Bs[b][sub][ch * 8]);                                \
            }                                                                \
    } while (0)

#define GEMM_COMPUTE_SUB(sub) do {                                           \
        short8 a[2], b[NFR];                                                 \
        _Pragma("unroll")                                                    \
        for (int mi = 0; mi < 2; ++mi)                                       \
            a[mi] = *(const short8*)&As[cur][sub][(wm + mi * 16 + cc) * 32 + g * 8]; \
        _Pragma("unroll")                                                    \
        for (int ni = 0; ni < NFR; ++ni)                                     \
            b[ni] = *(const short8*)&Bs[cur][sub][(wn + ni * 16 + cc) * 32 + g * 8]; \
        __builtin_amdgcn_s_setprio(1);                                       \
        _Pragma("unroll")                                                    \
        for (int mi = 0; mi < 2; ++mi)                                       \
            _Pragma("unroll")                                                \
            for (int ni = 0; ni < NFR; ++ni)                                 \
                acc[mi][ni] = __builtin_amdgcn_mfma_f32_16x16x32_bf16(       \
                    a[mi], b[ni], acc[mi][ni], 0, 0, 0);                     \
        __builtin_amdgcn_s_setprio(0);                                       \
    } while (0)

template <typename OutT, int BN>
__global__ __launch_bounds__(256) void gemm_bf16_db(
    const unsigned short* __restrict__ A, const unsigned short* __restrict__ Bt,
    OutT* __restrict__ C, int M, int N, int K, int lda, int ldc)
{
    constexpr int NFR = BN / 32;
    __shared__ unsigned short As[2][2][64 * 32];
    __shared__ unsigned short Bs[2][2][BN * 32];

    const int tid = threadIdx.x;
    const int l = tid & 63;
    const int g = l >> 4, cc = l & 15;
    const int w = tid >> 6;
    const int wm = (w >> 1) * 32, wn = (w & 1) * (BN / 2);

    const int nwg = gridDim.x * gridDim.y;
    const int wg = xcd_swz(blockIdx.y * gridDim.x + blockIdx.x, nwg);
    const int bm = (wg / gridDim.x) * 64;
    const int bn = (wg % gridDim.x) * BN;

    floatx4 acc[2][NFR];
#pragma unroll
    for (int i = 0; i < 2; i++)
#pragma unroll
        for (int j = 0; j < NFR; j++) acc[i][j] = (floatx4){0.f, 0.f, 0.f, 0.f};

    GEMM_STAGE(0, 0);
    __syncthreads();
    int cur = 0;

    for (int k0 = 0; k0 < K; k0 += 64) {
        if (k0 + 64 < K) GEMM_STAGE(cur ^ 1, k0 + 64);
        GEMM_COMPUTE_SUB(0);
        GEMM_COMPUTE_SUB(1);
        __syncthreads();
        cur ^= 1;
    }

#pragma unroll
    for (int mi = 0; mi < 2; ++mi)
#pragma unroll
        for (int ni = 0; ni < NFR; ++ni)
#pragma unroll
            for (int i = 0; i < 4; ++i) {
                int row = bm + wm + mi * 16 + g * 4 + i;
                int col = bn + wn + ni * 16 + cc;
                if (col < N) store_out(&C[(size_t)row * ldc + col], acc[mi][ni][i]);
            }
}

// Dual-output variant for the fused q_a|kv_a projection (64x128, BK=64).
__global__ __launch_bounds__(256) void gemm_bf16_dual(
    const unsigned short* __restrict__ A, const unsigned short* __restrict__ Bt,
    float* __restrict__ C0, float* __restrict__ C1,
    int M, int N, int K, int lda, int ldc0, int ldc1)
{
    constexpr int BN = 128;
    constexpr int NFR = 4;
    __shared__ unsigned short As[2][2][64 * 32];
    __shared__ unsigned short Bs[2][2][BN * 32];

    const int tid = threadIdx.x;
    const int l = tid & 63;
    const int g = l >> 4, cc = l & 15;
    const int w = tid >> 6;
    const int wm = (w >> 1) * 32, wn = (w & 1) * (BN / 2);

    const int nwg = gridDim.x * gridDim.y;
    const int wg = xcd_swz(blockIdx.y * gridDim.x + blockIdx.x, nwg);
    const int bm = (wg / gridDim.x) * 64;
    const int bn = (wg % gridDim.x) * BN;

    floatx4 acc[2][NFR];
#pragma unroll
    for (int i = 0; i < 2; i++)
#pragma unroll
        for (int j = 0; j < NFR; j++) acc[i][j] = (floatx4){0.f, 0.f, 0.f, 0.f};

    GEMM_STAGE(0, 0);
    __syncthreads();
    int cur = 0;

    for (int k0 = 0; k0 < K; k0 += 64) {
        if (k0 + 64 < K) GEMM_STAGE(cur ^ 1, k0 + 64);
        GEMM_COMPUTE_SUB(0);
        GEMM_COMPUTE_SUB(1);
        __syncthreads();
        cur ^= 1;
    }

#pragma unroll
    for (int mi = 0; mi < 2; ++mi)
#pragma unroll
        for (int ni = 0; ni < NFR; ++ni)
#pragma unroll
            for (int i = 0; i < 4; ++i) {
                int row = bm + wm + mi * 16 + g * 4 + i;
                int col = bn + wn + ni * 16 + cc;
                if (col < QLR_)
                    C0[(size_t)row * ldc0 + col] = acc[mi][ni][i];
                else if (col < N)
                    C1[(size_t)row * ldc1 + (col - QLR_)] = acc[mi][ni][i];
            }
}

// ---------------------------------------------------------------------------
// Paired GEMM (round-10 verified): q_b and kv_b in ONE launch. Blocks
// [0,nwg0) run GEMM0, [nwg0,nwg0+nwg1) run GEMM1.
// ---------------------------------------------------------------------------
__global__ __launch_bounds__(256) void gemm_bf16_pair(
    const unsigned short* __restrict__ A0, const unsigned short* __restrict__ Bt0,
    unsigned short* __restrict__ Cp0, int N0, int K0, int lda0, int ldc0, int gx0, int nwg0,
    const unsigned short* __restrict__ A1, const unsigned short* __restrict__ Bt1,
    unsigned short* __restrict__ Cp1, int N1, int K1, int lda1, int ldc1, int gx1, int nwg1)
{
    constexpr int BN = 128;
    constexpr int NFR = 4;
    __shared__ unsigned short As[2][2][64 * 32];
    __shared__ unsigned short Bs[2][2][BN * 32];

    const int tid = threadIdx.x;
    const int l = tid & 63;
    const int g = l >> 4, cc = l & 15;
    const int w = tid >> 6;
    const int wm = (w >> 1) * 32, wn = (w & 1) * (BN / 2);

    const int bid = blockIdx.x;
    const unsigned short *A, *Bt;
    unsigned short* C;
    int N, K, lda, ldc, wg, gx;
    if (bid < nwg0) {
        wg = xcd_swz(bid, nwg0); gx = gx0;
        A = A0; Bt = Bt0; C = Cp0; N = N0; K = K0; lda = lda0; ldc = ldc0;
    } else {
        wg = xcd_swz(bid - nwg0, nwg1); gx = gx1;
        A = A1; Bt = Bt1; C = Cp1; N = N1; K = K1; lda = lda1; ldc = ldc1;
    }
    const int bm = (wg / gx) * 64;
    const int bn = (wg % gx) * BN;

    floatx4 acc[2][NFR];
#pragma unroll
    for (int i = 0; i < 2; i++)
#pragma unroll
        for (int j = 0; j < NFR; j++) acc[i][j] = (floatx4){0.f, 0.f, 0.f, 0.f};

    GEMM_STAGE(0, 0);
    __syncthreads();
    int cur = 0;

    for (int k0 = 0; k0 < K; k0 += 64) {
        if (k0 + 64 < K) GEMM_STAGE(cur ^ 1, k0 + 64);
        GEMM_COMPUTE_SUB(0);
        GEMM_COMPUTE_SUB(1);
        __syncthreads();
        cur ^= 1;
    }

#pragma unroll
    for (int mi = 0; mi < 2; ++mi)
#pragma unroll
        for (int ni = 0; ni < NFR; ++ni)
#pragma unroll
            for (int i = 0; i < 4; ++i) {
                int row = bm + wm + mi * 16 + g * 4 + i;
                int col = bn + wn + ni * 16 + cc;
                if (col < N) C[(size_t)row * ldc + col] = f2bf(acc[mi][ni][i]);
            }
}

__global__ __launch_bounds__(256) void cast_bf16(
    const float* __restrict__ in, unsigned short* __restrict__ out, int n)
{
    int i = (blockIdx.x * 256 + threadIdx.x) * 4;
    if (i >= n) return;
    float4 v = *(const float4*)&in[i];
    ushort4 u;
    u.x = f2bf(v.x); u.y = f2bf(v.y); u.z = f2bf(v.z); u.w = f2bf(v.w);
    *(ushort4*)&out[i] = u;
}

__global__ __launch_bounds__(256) void transpose_cast(
    const float* __restrict__ W, unsigned short* __restrict__ Wt, int K, int N,
    float scl)
{
    __shared__ float t[32][33];
    const int n0 = blockIdx.x * 32, k0 = blockIdx.y * 32;
    const int tx = threadIdx.x & 31, ty4 = (threadIdx.x >> 5) * 4;
#pragma unroll
    for (int j = 0; j < 4; ++j)
        t[ty4 + j][tx] = W[(size_t)(k0 + ty4 + j) * N + n0 + tx];
    __syncthreads();
#pragma unroll
    for (int j = 0; j < 4; ++j)
        Wt[(size_t)(n0 + ty4 + j) * K + k0 + tx] = f2bf(t[tx][ty4 + j] * scl);
}

__global__ __launch_bounds__(256) void rmsnorm_bf16out(
    const float* __restrict__ x, const float* __restrict__ w,
    unsigned short* __restrict__ y, int cols, int xstride)
{
    const float* xr = x + (size_t)blockIdx.x * xstride;
    unsigned short* yr = y + (size_t)blockIdx.x * cols;
    const int tid = threadIdx.x;
    float ss = 0.f;
    for (int c = tid; c < cols; c += 256) { float v = xr[c]; ss += v * v; }
#pragma unroll
    for (int off = 32; off > 0; off >>= 1) ss += __shfl_xor(ss, off);
    __shared__ float red[4];
    if ((tid & 63) == 0) red[tid >> 6] = ss;
    __syncthreads();
    ss = red[0] + red[1] + red[2] + red[3];
    const float inv = rsqrtf(ss / (float)cols + 1e-6f);
    for (int c = tid; c < cols; c += 256) yr[c] = f2bf(xr[c] * inv * w[c]);
}

// Interleaved RoPE in place on bf16 q rot slices.
__global__ void rope_q_bf(unsigned short* __restrict__ q,
                          const float* __restrict__ cs, const float* __restrict__ sn)
{
    int t = blockIdx.x * 256 + threadIdx.x;
    int chunk = t >> 5, j = t & 31;
    int s = chunk >> 4, h = chunk & 15;
    unsigned short* x = q + (size_t)s * QW_ + h * DQK_ + DN_;
    float e = bf2f(x[2 * j]), o = bf2f(x[2 * j + 1]);
    float c = cs[s * DR_ + j], si = sn[s * DR_ + j];
    unsigned short u = f2bf(e * c - o * si);
    unsigned short v = f2bf(o * c + e * si);
    x[j] = u; x[j + 32] = v;
}

// ---------------------------------------------------------------------------
// prep_k: kg[h][s][192] bf16 = [k_pass(h) | rope(k_rot)], 16B-chunk XOR
// swizzle (chunk d8 stored at d8 ^ (s&7)) baked in (rule-21 pattern).
// ---------------------------------------------------------------------------
__global__ __launch_bounds__(256) void prep_k(
    const unsigned short* __restrict__ kvb, const float* __restrict__ ckv,
    const float* __restrict__ cs, const float* __restrict__ sn,
    unsigned short* __restrict__ kg)
{
    const int s = blockIdx.x, tid = threadIdx.x;
    __shared__ unsigned short rot[64];
    if (tid < 32) {
        int j = tid;
        const float* x = ckv + (size_t)s * CKVW_ + KVLR_;
        float e = x[2 * j], o = x[2 * j + 1];
        float c = cs[s * DR_ + j], si = sn[s * DR_ + j];
        rot[j] = f2bf(e * c - o * si);
        rot[j + 32] = f2bf(o * c + e * si);
    }
    __syncthreads();
    const int sw = s & 7;
    for (int ch = tid; ch < 384; ch += 256) {
        int hh = ch / 24, d8 = ch % 24;
        short8 v;
        if (d8 < 16)
            v = *(const short8*)&kvb[(size_t)s * KVW_ + hh * 256 + d8 * 8];
        else
            v = *(const short8*)&rot[(d8 - 16) * 8];
        int d8s = d8 ^ sw;
        *(short8*)&kg[((size_t)hh * S_ + s) * 192 + d8s * 8] = v;
    }
}

// ---------------------------------------------------------------------------
// transpose_v: vt[h*128+dv][s] <- kvb[s][h*256+128+dv]
// ---------------------------------------------------------------------------
__global__ __launch_bounds__(256) void transpose_v(
    const unsigned short* __restrict__ kvb, unsigned short* __restrict__ vt)
{
    __shared__ unsigned short t[32][36];
    const int dv0 = blockIdx.x * 32, s0 = blockIdx.y * 32, h = blockIdx.z;
    const int r = threadIdx.x >> 3, c4 = threadIdx.x & 7;
    ushort4 ld = *(const ushort4*)&kvb[(size_t)(s0 + r) * KVW_ + h * 256 + 128 + dv0 + c4 * 4];
    t[r][c4 * 4 + 0] = ld.x; t[r][c4 * 4 + 1] = ld.y;
    t[r][c4 * 4 + 2] = ld.z; t[r][c4 * 4 + 3] = ld.w;
    __syncthreads();
    ushort4 st;
    st.x = t[c4 * 4 + 0][r]; st.y = t[c4 * 4 + 1][r];
    st.z = t[c4 * 4 + 2][r]; st.w = t[c4 * 4 + 3][r];
    *(ushort4*)&vt[(size_t)(h * 128 + dv0 + r) * S_ + s0 + c4 * 4] = st;
}

// ---------------------------------------------------------------------------
// Flash attention v8 (round-9 verified BEST, 51.0 us): fully-staged inner
// loop (K AND V via global_load_lds, double-buffered), QBLK=64, 4 waves,
// 2-way BLOCK kv-split + merge_attn. bid&7 == h&7 pins each head to one XCD.
// LDS 45 KB -> 3 blocks/CU. Log2 softmax, T13 defer-rescale, cvt_pk P-pack
// through the wave-private Pw LDS buffer (round-11's shuffle variant was
// SLOWER — ds_bpermute serializes on the same LDS pipe; reverted).
// ---------------------------------------------------------------------------
__global__ __launch_bounds__(256, 3) void flash_attn7(
    const unsigned short* __restrict__ qg, const unsigned short* __restrict__ kg,
    const unsigned short* __restrict__ vt,
    unsigned short* __restrict__ op0, unsigned short* __restrict__ op1,
    float* __restrict__ mlp)
{
    const int bid = blockIdx.x;
    const int qblk = 31 - (bid >> 5);    // LPT: longest q-blocks first
    const int low5 = bid & 31;
    const int h = low5 & 15;             // bid&7 = h&7 -> head pinned to XCD
    const int sp = low5 >> 4;            // kv-split half
    const int pb = h * 32 + qblk;        // partial-buffer index

    // LDS: K[2][6144 us] + V[2][4096 us] + P[4][640 us] = 23040 us = 45 KB
    __shared__ unsigned short sm[2 * 6144 + 2 * 4096 + 4 * 640];
    unsigned short* Kb = sm;                     // [2][32 k][192 d] (XOR-swz)
    unsigned short* Vb = sm + 12288;             // [2][128 dv][32 k]
    const int tid = threadIdx.x;
    const int w = tid >> 6;              // 0..3 : q-strip
    const int l = tid & 63, g = l >> 4, cc = l & 15;
    unsigned short* Pw = sm + 20480 + w * 640;   // [16 q][40 kv]

    const int qmin = qblk * 64 + w * 16;
    const int q_lane = qmin + cc;        // this lane's q row
    const int wave_qmax = qmin + 15;
    const int HT = qblk + 1;             // tiles per split half
    const int kt_begin = sp * HT, kt_end = kt_begin + HT;

    const unsigned short* kh = kg + (size_t)h * S_ * 192;
    const unsigned short* vh = vt + (size_t)(h * 128) * S_;

    // Q fragments direct from global (once per block; small tx count)
    short8 qf[6];
    {
        const unsigned short* qb = qg + (size_t)q_lane * QW_ + h * DQK_;
#pragma unroll
        for (int k6 = 0; k6 < 6; ++k6)
            qf[k6] = *(const short8*)&qb[k6 * 32 + g * 8];
    }

    floatx4 accO[8];
#pragma unroll
    for (int nt = 0; nt < 8; ++nt) accO[nt] = (floatx4){0.f, 0.f, 0.f, 0.f};
    float m_r = -1e30f, l_r = 0.f;   // q-row = cc (replicated across g), log2 domain

    // coalesced K+V tile staging (kg pre-swizzled globally -> linear copy)
#define STAGE_KV(b, kt) do {                                             \
        const unsigned short* ksrc = kh + (size_t)(kt) * 32 * 192;       \
        _Pragma("unroll")                                                \
        for (int j = 0; j < 3; ++j) {                                    \
            int ch = j * 256 + tid;                                      \
            gload16(ksrc + ch * 8, Kb + (b) * 6144 + ch * 8);            \
        }                                                                \
        const int krow = (kt) * 32;                                      \
        _Pragma("unroll")                                                \
        for (int j = 0; j < 2; ++j) {                                    \
            int ch = j * 256 + tid;                                      \
            int dv = ch >> 2, j8 = ch & 3;                               \
            gload16(vh + (size_t)dv * S_ + krow + j8 * 8,                \
                    Vb + (b) * 4096 + ch * 8);                           \
        }                                                                \
    } while (0)

    STAGE_KV(0, kt_begin);
    int cur = 0;

    // wave-uniform loop bounds; per-wave guard inside
    for (int kt = kt_begin; kt < kt_end; ++kt) {
        const int krow0 = kt * 32;
        __syncthreads();   // staged data for kt ready (barrier drains vmcnt)
        if (kt + 1 < kt_end) STAGE_KV(cur ^ 1, kt + 1);

        if (krow0 <= wave_qmax) {
            const unsigned short* Kc = Kb + cur * 6144;
            const unsigned short* Vc = Vb + cur * 4096;
            const int swz = (cc & 7) << 3;

            floatx4 s0 = (floatx4){0.f, 0.f, 0.f, 0.f};
            floatx4 s1 = (floatx4){0.f, 0.f, 0.f, 0.f};
            __builtin_amdgcn_s_setprio(1);
#pragma unroll
            for (int k6 = 0; k6 < 6; ++k6) {
                short8 b0 = *(const short8*)&Kc[cc * 192 + ((k6 * 32 + g * 8) ^ swz)];
                short8 b1 = *(const short8*)&Kc[(16 + cc) * 192 + ((k6 * 32 + g * 8) ^ swz)];
                // SWAPPED: A = K rows, B = Q rows -> D[kv][q]
                s0 = __builtin_amdgcn_mfma_f32_16x16x32_bf16(b0, qf[k6], s0, 0, 0, 0);
                s1 = __builtin_amdgcn_mfma_f32_16x16x32_bf16(b1, qf[k6], s1, 0, 0, 0);
            }
            __builtin_amdgcn_s_setprio(0);

            // scores for q=cc (log2 domain; scale folded into wq_b)
            float v0[4], v1[4];
            if (krow0 + 31 <= qmin) {
#pragma unroll
                for (int i = 0; i < 4; ++i) { v0[i] = s0[i]; v1[i] = s1[i]; }
            } else {
#pragma unroll
                for (int i = 0; i < 4; ++i) {
                    v0[i] = (krow0 + g * 4 + i) <= q_lane ? s0[i] : -1e30f;
                    v1[i] = (krow0 + 16 + g * 4 + i) <= q_lane ? s1[i] : -1e30f;
                }
            }
            float mt = fmaxf(fmaxf(fmaxf(v0[0], v0[1]), fmaxf(v0[2], v0[3])),
                             fmaxf(fmaxf(v1[0], v1[1]), fmaxf(v1[2], v1[3])));
            mt = fmaxf(mt, __shfl_xor(mt, 16));
            mt = fmaxf(mt, __shfl_xor(mt, 32));

            // T13 defer-rescale: wave-uniform skip when max grows < 6 (log2)
            if (!__all(mt <= m_r + 6.0f)) {
                float mn = fmaxf(m_r, mt);
                float alpha = exp2f(m_r - mn);
                m_r = mn;
                l_r *= alpha;
                float aB[4];
#pragma unroll
                for (int i = 0; i < 4; ++i) aB[i] = __shfl(alpha, g * 4 + i);
#pragma unroll
                for (int nt = 0; nt < 8; ++nt)
#pragma unroll
                    for (int i = 0; i < 4; ++i) accO[nt][i] *= aB[i];
            }

            float p0[4], p1[4], ps = 0.f;
#pragma unroll
            for (int i = 0; i < 4; ++i) {
                p0[i] = exp2f(v0[i] - m_r);   // masked lanes: exp2(-huge) = 0
                p1[i] = exp2f(v1[i] - m_r);
                ps += p0[i] + p1[i];
            }
            ps += __shfl_xor(ps, 16);
            ps += __shfl_xor(ps, 32);
            l_r += ps;

            // write P[q=cc][kv] to wave-private LDS (same-wave reuse only);
            // bf16 pack via HW cvt_pk (RNE, identical to f2bf on [0,1] data)
            {
                unsigned pk00, pk01, pk10, pk11;
                asm("v_cvt_pk_bf16_f32 %0, %1, %2" : "=v"(pk00) : "v"(p0[0]), "v"(p0[1]));
                asm("v_cvt_pk_bf16_f32 %0, %1, %2" : "=v"(pk01) : "v"(p0[2]), "v"(p0[3]));
                asm("v_cvt_pk_bf16_f32 %0, %1, %2" : "=v"(pk10) : "v"(p1[0]), "v"(p1[1]));
                asm("v_cvt_pk_bf16_f32 %0, %1, %2" : "=v"(pk11) : "v"(p1[2]), "v"(p1[3]));
                uint2 w0, w1;
                w0.x = pk00; w0.y = pk01;
                w1.x = pk10; w1.y = pk11;
                *(uint2*)&Pw[cc * 40 + g * 4] = w0;
                *(uint2*)&Pw[cc * 40 + 16 + g * 4] = w1;
            }

            short8 pf = *(const short8*)&Pw[cc * 40 + g * 8];
            __builtin_amdgcn_s_setprio(1);
#pragma unroll
            for (int nt = 0; nt < 8; ++nt) {
                short8 vr = *(const short8*)&Vc[(nt * 16 + cc) * 32 + g * 8];
                accO[nt] = __builtin_amdgcn_mfma_f32_16x16x32_bf16(pf, vr, accO[nt], 0, 0, 0);
            }
            __builtin_amdgcn_s_setprio(0);
        }
        cur ^= 1;
    }
#undef STAGE_KV

    // ---- emit unnormalized partial + (m,l) ----
    float mB[4], lB[4];
#pragma unroll
    for (int i = 0; i < 4; ++i) {
        int src = (g << 4) | (g * 4 + i);   // lane with cc == g*4+i (same g)
        mB[i] = __shfl(m_r, src);
        lB[i] = __shfl(l_r, src);
    }
    unsigned short* op = sp ? op1 : op0;
#pragma unroll
    for (int nt = 0; nt < 8; ++nt)
#pragma unroll
        for (int i = 0; i < 4; ++i)
            op[(size_t)pb * 8192 + (w * 16 + g * 4 + i) * 128 + nt * 16 + cc] =
                f2bf(accO[nt][i]);
    if (cc == 0) {
#pragma unroll
        for (int i = 0; i < 4; ++i) {
            size_t mi = ((size_t)(sp * 512 + pb) * 64 + w * 16 + g * 4 + i) * 2;
            mlp[mi + 0] = mB[i];
            mlp[mi + 1] = lB[i];
        }
    }
}

// ---------------------------------------------------------------------------
// merge_attn: combine the two kv-split partials per (h,qblk) -> ao bf16.
// grid 512 blocks x 256 threads; thread = (row = tid>>2, 32-col segment).
// ---------------------------------------------------------------------------
__global__ __launch_bounds__(256) void merge_attn(
    const unsigned short* __restrict__ op0, const unsigned short* __restrict__ op1,
    const float* __restrict__ mlp, unsigned short* __restrict__ ao)
{
    const int pb = blockIdx.x;           // h*32 + qblk
    const int h = pb >> 5, qblk = pb & 31;
    const int tid = threadIdx.x;
    const int row = tid >> 2, c0 = (tid & 3) * 32;

    const size_t mi0 = ((size_t)pb * 64 + row) * 2;
    const size_t mi1 = ((size_t)(512 + pb) * 64 + row) * 2;
    float m0 = mlp[mi0 + 0], l0 = mlp[mi0 + 1];
    float m1 = mlp[mi1 + 0], l1 = mlp[mi1 + 1];
    float mf = fmaxf(m0, m1);
    float e0 = exp2f(m0 - mf), e1 = exp2f(m1 - mf);
    float inv = 1.f / (l0 * e0 + l1 * e1);
    float w0 = e0 * inv, w1 = e1 * inv;

    const size_t pbase = (size_t)pb * 8192 + row * 128 + c0;
    unsigned short* dst = ao + (size_t)(qblk * 64 + row) * (NH_ * DV_) + h * DV_ + c0;
#pragma unroll
    for (int j = 0; j < 4; ++j) {
        short8 a = *(const short8*)&op0[pbase + j * 8];
        short8 b = *(const short8*)&op1[pbase + j * 8];
        short8 o;
#pragma unroll
        for (int k = 0; k < 8; ++k)
            o[k] = (short)f2bf(bf2f((unsigned short)a[k]) * w0 +
                               bf2f((unsigned short)b[k]) * w1);
        *(short8*)&dst[j * 8] = o;
    }
}

// ---------------------------------------------------------------------------
extern "C" void kernel_launch(void* const* d_in, const int* in_sizes, int n_in,
                              void* d_out, int out_size, void* d_ws, size_t ws_size,
                              hipStream_t stream)
{
    const float* hs    = (const float*)d_in[0];
    const float* cosp  = (const float*)d_in[1];
    const float* sinp  = (const float*)d_in[2];
    const float* wq_a  = (const float*)d_in[3];
    const float* q_ln  = (const float*)d_in[4];
    const float* wq_b  = (const float*)d_in[5];
    const float* wkv_a = (const float*)d_in[6];
    const float* kv_ln = (const float*)d_in[7];
    const float* wkv_b = (const float*)d_in[8];
    const float* wo    = (const float*)d_in[9];
    float* out = (float*)d_out;

    char* ws = (char*)d_ws;
    float*          qa     = (float*)(ws);                        // [2048][1536] f32 (dead after rms -> wbt2/kg)
    float*          ckv    = (float*)(ws + 12582912);             // [2048][576]  f32 (dead after prep_k -> mlp)
    unsigned short* q_bf   = (unsigned short*)(ws + 17301504);    // [2048][3072] bf16
    unsigned short* kvb    = (unsigned short*)(ws + 29884416);    // [2048][4096] bf16
    unsigned short* hs_bf  = (unsigned short*)(ws + 46661632);    // [2048][2048] bf16 (dead after fused gemm -> vtb)
    unsigned short* qa_bf  = (unsigned short*)(ws + 55050240);    // [2048][1536] bf16 (dead after q_b gemm -> op0)
    unsigned short* ckv_bf = (unsigned short*)(ws + 61341696);    // [2048][512]  bf16
    unsigned short* ao_bf  = (unsigned short*)(ws + 63438848);    // [2048][2048] bf16
    unsigned short* wt     = (unsigned short*)(ws + 71827456);    // [3072][1536] bf16 max (dead during flash -> op1)
    unsigned short* kg     = (unsigned short*)qa;                 // [16][2048][192] bf16
    unsigned short* vtb    = hs_bf;                               // [16*128][2048] bf16
    unsigned short* wbt2   = (unsigned short*)qa;                 // [4096][512] bf16 (wkv_b^T; qa dead, kg written later)

    // flash partials (alias dead regions during attention):
    unsigned short* op0 = qa_bf;                       // 512*8192 bf16 = 8.39 MB
    unsigned short* op1 = wt;                          // 512*8192 bf16 = 8.39 MB
    float*          mlp = ckv;                         // 2*512*64*2 f32 = 0.5 MB

    // scores scale * log2(e), folded into wq_b (q only feeds QK^T; RoPE linear)
    const float qscale = 0.07216878364870322f * 1.4426950408889634f;

    // hs -> bf16
    cast_bf16<<<(S_ * H_) / 1024, 256, 0, stream>>>(hs, hs_bf, S_ * H_);

    // fused q_a|kv_a projection: Bt = [wq_a^T (1536 rows) | wkv_a^T (576 rows)]
    transpose_cast<<<dim3(QLR_ / 32, H_ / 32), 256, 0, stream>>>(wq_a, wt, H_, QLR_, 1.f);
    transpose_cast<<<dim3(CKVW_ / 32, H_ / 32), 256, 0, stream>>>(
        wkv_a, wt + (size_t)QLR_ * H_, H_, CKVW_, 1.f);
    gemm_bf16_dual<<<dim3((QLR_ + CKVW_ + 127) / 128, S_ / 64), 256, 0, stream>>>(
        hs_bf, wt, qa, ckv, S_, QLR_ + CKVW_, H_, H_, QLR_, CKVW_);
    rmsnorm_bf16out<<<S_, 256, 0, stream>>>(qa, q_ln, qa_bf, QLR_, QLR_);
    rmsnorm_bf16out<<<S_, 256, 0, stream>>>(ckv, kv_ln, ckv_bf, KVLR_, CKVW_);

    // q_b + kv_b in ONE launch (round-10): wq_b^T -> wt, wkv_b^T -> wbt2
    transpose_cast<<<dim3(QW_ / 32, QLR_ / 32), 256, 0, stream>>>(wq_b, wt, QLR_, QW_, qscale);
    transpose_cast<<<dim3(KVW_ / 32, KVLR_ / 32), 256, 0, stream>>>(wkv_b, wbt2, KVLR_, KVW_, 1.f);
    gemm_bf16_pair<<<768 + 1024, 256, 0, stream>>>(
        qa_bf, wt, q_bf, QW_, QLR_, QLR_, QW_, QW_ / 128, 768,
        ckv_bf, wbt2, kvb, KVW_, KVLR_, KVLR_, KVW_, KVW_ / 128, 1024);
    rope_q_bf<<<(S_ * NH_ * 32) / 256, 256, 0, stream>>>(q_bf, cosp, sinp);

    // build kg (swizzled, rope fused; overwrites wbt2) and vt
    prep_k<<<S_, 256, 0, stream>>>(kvb, ckv, cosp, sinp, kg);
    transpose_v<<<dim3(4, 64, 16), 256, 0, stream>>>(kvb, vtb);

    // attention: fully-staged inner loop, 2-way block kv-split, 3 blocks/CU
    flash_attn7<<<1024, 256, 0, stream>>>(q_bf, kg, vtb, op0, op1, mlp);
    merge_attn<<<512, 256, 0, stream>>>(op0, op1, mlp, ao_bf);

    // output projection (wt reused AFTER merge has consumed op1)
    transpose_cast<<<dim3(H_ / 32, H_ / 32), 256, 0, stream>>>(wo, wt, H_, H_, 1.f);
    gemm_bf16_db<float, 128><<<dim3(H_ / 128, S_ / 64), 256, 0, stream>>>(
        ao_bf, wt, out, S_, H_, NH_ * DV_, NH_ * DV_, H_);
}

// Round 14
// 211.498 us; speedup vs baseline: 1.0471x; 1.0126x over previous
//
#include <hip/hip_runtime.h>
#include <hip/hip_bf16.h>
#include <stdint.h>

// Problem constants
#define S_    2048
#define H_    2048
#define NH_   16
#define QLR_  1536
#define KVLR_ 512
#define DR_   64
#define DN_   128
#define DV_   128
#define DQK_  192            // DN + DR
#define QW_   (NH_*DQK_)     // 3072
#define KVW_  (NH_*(DN_+DV_))// 4096
#define CKVW_ (KVLR_+DR_)    // 576

typedef __attribute__((ext_vector_type(8))) short short8;
typedef __attribute__((ext_vector_type(4))) float floatx4;

__device__ __forceinline__ unsigned short f2bf(float f) {
    unsigned u = __float_as_uint(f);
    unsigned r = u + 0x7fffu + ((u >> 16) & 1u);
    return (unsigned short)(r >> 16);
}
__device__ __forceinline__ float bf2f(unsigned short h) {
    return __uint_as_float(((unsigned)h) << 16);
}
__device__ __forceinline__ void store_out(float* p, float v) { *p = v; }
__device__ __forceinline__ void store_out(unsigned short* p, float v) { *p = f2bf(v); }

// async global->LDS, 16 bytes per lane (lane-linear dest)
typedef const __attribute__((address_space(1))) unsigned int* gas_ptr;
typedef __attribute__((address_space(3))) unsigned int* las_ptr;
__device__ __forceinline__ void gload16(const void* g, void* l) {
    __builtin_amdgcn_global_load_lds((gas_ptr)g, (las_ptr)l, 16, 0, 0);
}

// bijective XCD-aware swizzle (m204): orig linear wg -> swizzled wg
__device__ __forceinline__ int xcd_swz(int orig, int nwg) {
    int q8 = nwg >> 3, r8 = nwg & 7;
    int xcd = orig & 7, jj = orig >> 3;
    return (xcd < r8 ? xcd * (q8 + 1) : r8 * (q8 + 1) + (xcd - r8) * q8) + jj;
}

// ---------------------------------------------------------------------------
// bf16 MFMA GEMM, double-buffered, 64x128 tile, BK=64 (round-6/9 verified).
// Used for dual (grid 544) and out-proj (grid 512) where BM=128 would
// grid-starve. C[M,N] = A[M,K] @ Bt[N,K]^T.
// ---------------------------------------------------------------------------
#define GEMM_STAGE(b, k0) do {                                               \
        _Pragma("unroll")                                                    \
        for (int sub = 0; sub < 2; ++sub) {                                  \
            int m = tid >> 2, k8 = tid & 3;                                  \
            gload16(A + (size_t)(bm + m) * lda + (k0) + sub * 32 + k8 * 8,   \
                    &As[b][sub][tid * 8]);                                   \
        }                                                                    \
        _Pragma("unroll")                                                    \
        for (int sub = 0; sub < 2; ++sub)                                    \
            _Pragma("unroll")                                                \
            for (int j = 0; j < BN / 64; ++j) {                              \
                int ch = j * 256 + tid;                                      \
                int n = ch >> 2, k8 = ch & 3;                                \
                int nrow = bn + n; if (nrow >= N) nrow = N - 1;              \
                gload16(Bt + (size_t)nrow * K + (k0) + sub * 32 + k8 * 8,    \
                        &Bs[b][sub][ch * 8]);                                \
            }                                                                \
    } while (0)

#define GEMM_COMPUTE_SUB(sub) do {                                           \
        short8 a[2], b[NFR];                                                 \
        _Pragma("unroll")                                                    \
        for (int mi = 0; mi < 2; ++mi)                                       \
            a[mi] = *(const short8*)&As[cur][sub][(wm + mi * 16 + cc) * 32 + g * 8]; \
        _Pragma("unroll")                                                    \
        for (int ni = 0; ni < NFR; ++ni)                                     \
            b[ni] = *(const short8*)&Bs[cur][sub][(wn + ni * 16 + cc) * 32 + g * 8]; \
        __builtin_amdgcn_s_setprio(1);                                       \
        _Pragma("unroll")                                                    \
        for (int mi = 0; mi < 2; ++mi)                                       \
            _Pragma("unroll")                                                \
            for (int ni = 0; ni < NFR; ++ni)                                 \
                acc[mi][ni] = __builtin_amdgcn_mfma_f32_16x16x32_bf16(       \
                    a[mi], b[ni], acc[mi][ni], 0, 0, 0);                     \
        __builtin_amdgcn_s_setprio(0);                                       \
    } while (0)

template <typename OutT, int BN>
__global__ __launch_bounds__(256) void gemm_bf16_db(
    const unsigned short* __restrict__ A, const unsigned short* __restrict__ Bt,
    OutT* __restrict__ C, int M, int N, int K, int lda, int ldc)
{
    constexpr int NFR = BN / 32;
    __shared__ unsigned short As[2][2][64 * 32];
    __shared__ unsigned short Bs[2][2][BN * 32];

    const int tid = threadIdx.x;
    const int l = tid & 63;
    const int g = l >> 4, cc = l & 15;
    const int w = tid >> 6;
    const int wm = (w >> 1) * 32, wn = (w & 1) * (BN / 2);

    const int nwg = gridDim.x * gridDim.y;
    const int wg = xcd_swz(blockIdx.y * gridDim.x + blockIdx.x, nwg);
    const int bm = (wg / gridDim.x) * 64;
    const int bn = (wg % gridDim.x) * BN;

    floatx4 acc[2][NFR];
#pragma unroll
    for (int i = 0; i < 2; i++)
#pragma unroll
        for (int j = 0; j < NFR; j++) acc[i][j] = (floatx4){0.f, 0.f, 0.f, 0.f};

    GEMM_STAGE(0, 0);
    __syncthreads();
    int cur = 0;

    for (int k0 = 0; k0 < K; k0 += 64) {
        if (k0 + 64 < K) GEMM_STAGE(cur ^ 1, k0 + 64);
        GEMM_COMPUTE_SUB(0);
        GEMM_COMPUTE_SUB(1);
        __syncthreads();
        cur ^= 1;
    }

#pragma unroll
    for (int mi = 0; mi < 2; ++mi)
#pragma unroll
        for (int ni = 0; ni < NFR; ++ni)
#pragma unroll
            for (int i = 0; i < 4; ++i) {
                int row = bm + wm + mi * 16 + g * 4 + i;
                int col = bn + wn + ni * 16 + cc;
                if (col < N) store_out(&C[(size_t)row * ldc + col], acc[mi][ni][i]);
            }
}

// Dual-output variant for the fused q_a|kv_a projection (64x128, BK=64).
__global__ __launch_bounds__(256) void gemm_bf16_dual(
    const unsigned short* __restrict__ A, const unsigned short* __restrict__ Bt,
    float* __restrict__ C0, float* __restrict__ C1,
    int M, int N, int K, int lda, int ldc0, int ldc1)
{
    constexpr int BN = 128;
    constexpr int NFR = 4;
    __shared__ unsigned short As[2][2][64 * 32];
    __shared__ unsigned short Bs[2][2][BN * 32];

    const int tid = threadIdx.x;
    const int l = tid & 63;
    const int g = l >> 4, cc = l & 15;
    const int w = tid >> 6;
    const int wm = (w >> 1) * 32, wn = (w & 1) * (BN / 2);

    const int nwg = gridDim.x * gridDim.y;
    const int wg = xcd_swz(blockIdx.y * gridDim.x + blockIdx.x, nwg);
    const int bm = (wg / gridDim.x) * 64;
    const int bn = (wg % gridDim.x) * BN;

    floatx4 acc[2][NFR];
#pragma unroll
    for (int i = 0; i < 2; i++)
#pragma unroll
        for (int j = 0; j < NFR; j++) acc[i][j] = (floatx4){0.f, 0.f, 0.f, 0.f};

    GEMM_STAGE(0, 0);
    __syncthreads();
    int cur = 0;

    for (int k0 = 0; k0 < K; k0 += 64) {
        if (k0 + 64 < K) GEMM_STAGE(cur ^ 1, k0 + 64);
        GEMM_COMPUTE_SUB(0);
        GEMM_COMPUTE_SUB(1);
        __syncthreads();
        cur ^= 1;
    }

#pragma unroll
    for (int mi = 0; mi < 2; ++mi)
#pragma unroll
        for (int ni = 0; ni < NFR; ++ni)
#pragma unroll
            for (int i = 0; i < 4; ++i) {
                int row = bm + wm + mi * 16 + g * 4 + i;
                int col = bn + wn + ni * 16 + cc;
                if (col < QLR_)
                    C0[(size_t)row * ldc0 + col] = acc[mi][ni][i];
                else if (col < N)
                    C1[(size_t)row * ldc1 + (col - QLR_)] = acc[mi][ni][i];
            }
}

// ---------------------------------------------------------------------------
// Paired GEMM (round-13): q_b and kv_b in ONE launch, 128x128 tile, BK=32
// (the m97-verified dense structure). Pair fusion gives 384+512 = 896 blocks
// (~3.5/CU) so the 128-wide tile no longer grid-starves (R5's reason to
// shrink it). 16 MFMA/wave/barrier at 32 KB LDS.
// ---------------------------------------------------------------------------
#define PAIR_STAGE(b, k0) do {                                               \
        _Pragma("unroll")                                                    \
        for (int j = 0; j < 2; ++j) {                                        \
            int ch = j * 256 + tid;                                          \
            int m = ch >> 2, k8 = ch & 3;                                    \
            gload16(A + (size_t)(bm + m) * lda + (k0) + k8 * 8,              \
                    &As[b][ch * 8]);                                         \
        }                                                                    \
        _Pragma("unroll")                                                    \
        for (int j = 0; j < 2; ++j) {                                        \
            int ch = j * 256 + tid;                                          \
            int n = ch >> 2, k8 = ch & 3;                                    \
            int nrow = bn + n; if (nrow >= N) nrow = N - 1;                  \
            gload16(Bt + (size_t)nrow * K + (k0) + k8 * 8,                   \
                    &Bs[b][ch * 8]);                                         \
        }                                                                    \
    } while (0)

__global__ __launch_bounds__(256) void gemm_bf16_pair(
    const unsigned short* __restrict__ A0, const unsigned short* __restrict__ Bt0,
    unsigned short* __restrict__ Cp0, int N0, int K0, int lda0, int ldc0, int gx0, int nwg0,
    const unsigned short* __restrict__ A1, const unsigned short* __restrict__ Bt1,
    unsigned short* __restrict__ Cp1, int N1, int K1, int lda1, int ldc1, int gx1, int nwg1)
{
    __shared__ unsigned short As[2][128 * 32];
    __shared__ unsigned short Bs[2][128 * 32];

    const int tid = threadIdx.x;
    const int l = tid & 63;
    const int g = l >> 4, cc = l & 15;
    const int w = tid >> 6;
    const int wm = (w >> 1) * 64, wn = (w & 1) * 64;

    const int bid = blockIdx.x;
    const unsigned short *A, *Bt;
    unsigned short* C;
    int N, K, lda, ldc, wg, gx;
    if (bid < nwg0) {
        wg = xcd_swz(bid, nwg0); gx = gx0;
        A = A0; Bt = Bt0; C = Cp0; N = N0; K = K0; lda = lda0; ldc = ldc0;
    } else {
        wg = xcd_swz(bid - nwg0, nwg1); gx = gx1;
        A = A1; Bt = Bt1; C = Cp1; N = N1; K = K1; lda = lda1; ldc = ldc1;
    }
    const int bm = (wg / gx) * 128;
    const int bn = (wg % gx) * 128;

    floatx4 acc[4][4];
#pragma unroll
    for (int i = 0; i < 4; i++)
#pragma unroll
        for (int j = 0; j < 4; j++) acc[i][j] = (floatx4){0.f, 0.f, 0.f, 0.f};

    PAIR_STAGE(0, 0);
    __syncthreads();
    int cur = 0;

    for (int k0 = 0; k0 < K; k0 += 32) {
        if (k0 + 32 < K) PAIR_STAGE(cur ^ 1, k0 + 32);

        short8 a[4], b[4];
#pragma unroll
        for (int mi = 0; mi < 4; ++mi)
            a[mi] = *(const short8*)&As[cur][(wm + mi * 16 + cc) * 32 + g * 8];
#pragma unroll
        for (int ni = 0; ni < 4; ++ni)
            b[ni] = *(const short8*)&Bs[cur][(wn + ni * 16 + cc) * 32 + g * 8];
        __builtin_amdgcn_s_setprio(1);
#pragma unroll
        for (int mi = 0; mi < 4; ++mi)
#pragma unroll
            for (int ni = 0; ni < 4; ++ni)
                acc[mi][ni] = __builtin_amdgcn_mfma_f32_16x16x32_bf16(
                    a[mi], b[ni], acc[mi][ni], 0, 0, 0);
        __builtin_amdgcn_s_setprio(0);
        __syncthreads();
        cur ^= 1;
    }

#pragma unroll
    for (int mi = 0; mi < 4; ++mi)
#pragma unroll
        for (int ni = 0; ni < 4; ++ni)
#pragma unroll
            for (int i = 0; i < 4; ++i) {
                int row = bm + wm + mi * 16 + g * 4 + i;
                int col = bn + wn + ni * 16 + cc;
                if (col < N) C[(size_t)row * ldc + col] = f2bf(acc[mi][ni][i]);
            }
}

__global__ __launch_bounds__(256) void cast_bf16(
    const float* __restrict__ in, unsigned short* __restrict__ out, int n)
{
    int i = (blockIdx.x * 256 + threadIdx.x) * 4;
    if (i >= n) return;
    float4 v = *(const float4*)&in[i];
    ushort4 u;
    u.x = f2bf(v.x); u.y = f2bf(v.y); u.z = f2bf(v.z); u.w = f2bf(v.w);
    *(ushort4*)&out[i] = u;
}

__global__ __launch_bounds__(256) void transpose_cast(
    const float* __restrict__ W, unsigned short* __restrict__ Wt, int K, int N,
    float scl)
{
    __shared__ float t[32][33];
    const int n0 = blockIdx.x * 32, k0 = blockIdx.y * 32;
    const int tx = threadIdx.x & 31, ty4 = (threadIdx.x >> 5) * 4;
#pragma unroll
    for (int j = 0; j < 4; ++j)
        t[ty4 + j][tx] = W[(size_t)(k0 + ty4 + j) * N + n0 + tx];
    __syncthreads();
#pragma unroll
    for (int j = 0; j < 4; ++j)
        Wt[(size_t)(n0 + ty4 + j) * K + k0 + tx] = f2bf(t[tx][ty4 + j] * scl);
}

__global__ __launch_bounds__(256) void rmsnorm_bf16out(
    const float* __restrict__ x, const float* __restrict__ w,
    unsigned short* __restrict__ y, int cols, int xstride)
{
    const float* xr = x + (size_t)blockIdx.x * xstride;
    unsigned short* yr = y + (size_t)blockIdx.x * cols;
    const int tid = threadIdx.x;
    float ss = 0.f;
    for (int c = tid; c < cols; c += 256) { float v = xr[c]; ss += v * v; }
#pragma unroll
    for (int off = 32; off > 0; off >>= 1) ss += __shfl_xor(ss, off);
    __shared__ float red[4];
    if ((tid & 63) == 0) red[tid >> 6] = ss;
    __syncthreads();
    ss = red[0] + red[1] + red[2] + red[3];
    const float inv = rsqrtf(ss / (float)cols + 1e-6f);
    for (int c = tid; c < cols; c += 256) yr[c] = f2bf(xr[c] * inv * w[c]);
}

// Interleaved RoPE in place on bf16 q rot slices.
__global__ void rope_q_bf(unsigned short* __restrict__ q,
                          const float* __restrict__ cs, const float* __restrict__ sn)
{
    int t = blockIdx.x * 256 + threadIdx.x;
    int chunk = t >> 5, j = t & 31;
    int s = chunk >> 4, h = chunk & 15;
    unsigned short* x = q + (size_t)s * QW_ + h * DQK_ + DN_;
    float e = bf2f(x[2 * j]), o = bf2f(x[2 * j + 1]);
    float c = cs[s * DR_ + j], si = sn[s * DR_ + j];
    unsigned short u = f2bf(e * c - o * si);
    unsigned short v = f2bf(o * c + e * si);
    x[j] = u; x[j + 32] = v;
}

// ---------------------------------------------------------------------------
// prep_k: kg[h][s][192] bf16 = [k_pass(h) | rope(k_rot)], 16B-chunk XOR
// swizzle (chunk d8 stored at d8 ^ (s&7)) baked in (rule-21 pattern).
// ---------------------------------------------------------------------------
__global__ __launch_bounds__(256) void prep_k(
    const unsigned short* __restrict__ kvb, const float* __restrict__ ckv,
    const float* __restrict__ cs, const float* __restrict__ sn,
    unsigned short* __restrict__ kg)
{
    const int s = blockIdx.x, tid = threadIdx.x;
    __shared__ unsigned short rot[64];
    if (tid < 32) {
        int j = tid;
        const float* x = ckv + (size_t)s * CKVW_ + KVLR_;
        float e = x[2 * j], o = x[2 * j + 1];
        float c = cs[s * DR_ + j], si = sn[s * DR_ + j];
        rot[j] = f2bf(e * c - o * si);
        rot[j + 32] = f2bf(o * c + e * si);
    }
    __syncthreads();
    const int sw = s & 7;
    for (int ch = tid; ch < 384; ch += 256) {
        int hh = ch / 24, d8 = ch % 24;
        short8 v;
        if (d8 < 16)
            v = *(const short8*)&kvb[(size_t)s * KVW_ + hh * 256 + d8 * 8];
        else
            v = *(const short8*)&rot[(d8 - 16) * 8];
        int d8s = d8 ^ sw;
        *(short8*)&kg[((size_t)hh * S_ + s) * 192 + d8s * 8] = v;
    }
}

// ---------------------------------------------------------------------------
// transpose_v: vt[h*128+dv][s] <- kvb[s][h*256+128+dv]
// ---------------------------------------------------------------------------
__global__ __launch_bounds__(256) void transpose_v(
    const unsigned short* __restrict__ kvb, unsigned short* __restrict__ vt)
{
    __shared__ unsigned short t[32][36];
    const int dv0 = blockIdx.x * 32, s0 = blockIdx.y * 32, h = blockIdx.z;
    const int r = threadIdx.x >> 3, c4 = threadIdx.x & 7;
    ushort4 ld = *(const ushort4*)&kvb[(size_t)(s0 + r) * KVW_ + h * 256 + 128 + dv0 + c4 * 4];
    t[r][c4 * 4 + 0] = ld.x; t[r][c4 * 4 + 1] = ld.y;
    t[r][c4 * 4 + 2] = ld.z; t[r][c4 * 4 + 3] = ld.w;
    __syncthreads();
    ushort4 st;
    st.x = t[c4 * 4 + 0][r]; st.y = t[c4 * 4 + 1][r];
    st.z = t[c4 * 4 + 2][r]; st.w = t[c4 * 4 + 3][r];
    *(ushort4*)&vt[(size_t)(h * 128 + dv0 + r) * S_ + s0 + c4 * 4] = st;
}

// ---------------------------------------------------------------------------
// Flash attention v8 (round-9 verified BEST, 51.0 us): fully-staged inner
// loop (K AND V via global_load_lds, double-buffered), QBLK=64, 4 waves,
// 2-way BLOCK kv-split + merge_attn. bid&7 == h&7 pins each head to one XCD.
// LDS 45 KB -> 3 blocks/CU. Log2 softmax, T13 defer-rescale, cvt_pk P-pack
// through the wave-private Pw LDS buffer.
// ---------------------------------------------------------------------------
__global__ __launch_bounds__(256, 3) void flash_attn7(
    const unsigned short* __restrict__ qg, const unsigned short* __restrict__ kg,
    const unsigned short* __restrict__ vt,
    unsigned short* __restrict__ op0, unsigned short* __restrict__ op1,
    float* __restrict__ mlp)
{
    const int bid = blockIdx.x;
    const int qblk = 31 - (bid >> 5);    // LPT: longest q-blocks first
    const int low5 = bid & 31;
    const int h = low5 & 15;             // bid&7 = h&7 -> head pinned to XCD
    const int sp = low5 >> 4;            // kv-split half
    const int pb = h * 32 + qblk;        // partial-buffer index

    // LDS: K[2][6144 us] + V[2][4096 us] + P[4][640 us] = 23040 us = 45 KB
    __shared__ unsigned short sm[2 * 6144 + 2 * 4096 + 4 * 640];
    unsigned short* Kb = sm;                     // [2][32 k][192 d] (XOR-swz)
    unsigned short* Vb = sm + 12288;             // [2][128 dv][32 k]
    const int tid = threadIdx.x;
    const int w = tid >> 6;              // 0..3 : q-strip
    const int l = tid & 63, g = l >> 4, cc = l & 15;
    unsigned short* Pw = sm + 20480 + w * 640;   // [16 q][40 kv]

    const int qmin = qblk * 64 + w * 16;
    const int q_lane = qmin + cc;        // this lane's q row
    const int wave_qmax = qmin + 15;
    const int HT = qblk + 1;             // tiles per split half
    const int kt_begin = sp * HT, kt_end = kt_begin + HT;

    const unsigned short* kh = kg + (size_t)h * S_ * 192;
    const unsigned short* vh = vt + (size_t)(h * 128) * S_;

    // Q fragments direct from global (once per block; small tx count)
    short8 qf[6];
    {
        const unsigned short* qb = qg + (size_t)q_lane * QW_ + h * DQK_;
#pragma unroll
        for (int k6 = 0; k6 < 6; ++k6)
            qf[k6] = *(const short8*)&qb[k6 * 32 + g * 8];
    }

    floatx4 accO[8];
#pragma unroll
    for (int nt = 0; nt < 8; ++nt) accO[nt] = (floatx4){0.f, 0.f, 0.f, 0.f};
    float m_r = -1e30f, l_r = 0.f;   // q-row = cc (replicated across g), log2 domain

    // coalesced K+V tile staging (kg pre-swizzled globally -> linear copy)
#define STAGE_KV(b, kt) do {                                             \
        const unsigned short* ksrc = kh + (size_t)(kt) * 32 * 192;       \
        _Pragma("unroll")                                                \
        for (int j = 0; j < 3; ++j) {                                    \
            int ch = j * 256 + tid;                                      \
            gload16(ksrc + ch * 8, Kb + (b) * 6144 + ch * 8);            \
        }                                                                \
        const int krow = (kt) * 32;                                      \
        _Pragma("unroll")                                                \
        for (int j = 0; j < 2; ++j) {                                    \
            int ch = j * 256 + tid;                                      \
            int dv = ch >> 2, j8 = ch & 3;                               \
            gload16(vh + (size_t)dv * S_ + krow + j8 * 8,                \
                    Vb + (b) * 4096 + ch * 8);                           \
        }                                                                \
    } while (0)

    STAGE_KV(0, kt_begin);
    int cur = 0;

    // wave-uniform loop bounds; per-wave guard inside
    for (int kt = kt_begin; kt < kt_end; ++kt) {
        const int krow0 = kt * 32;
        __syncthreads();   // staged data for kt ready (barrier drains vmcnt)
        if (kt + 1 < kt_end) STAGE_KV(cur ^ 1, kt + 1);

        if (krow0 <= wave_qmax) {
            const unsigned short* Kc = Kb + cur * 6144;
            const unsigned short* Vc = Vb + cur * 4096;
            const int swz = (cc & 7) << 3;

            floatx4 s0 = (floatx4){0.f, 0.f, 0.f, 0.f};
            floatx4 s1 = (floatx4){0.f, 0.f, 0.f, 0.f};
            __builtin_amdgcn_s_setprio(1);
#pragma unroll
            for (int k6 = 0; k6 < 6; ++k6) {
                short8 b0 = *(const short8*)&Kc[cc * 192 + ((k6 * 32 + g * 8) ^ swz)];
                short8 b1 = *(const short8*)&Kc[(16 + cc) * 192 + ((k6 * 32 + g * 8) ^ swz)];
                // SWAPPED: A = K rows, B = Q rows -> D[kv][q]
                s0 = __builtin_amdgcn_mfma_f32_16x16x32_bf16(b0, qf[k6], s0, 0, 0, 0);
                s1 = __builtin_amdgcn_mfma_f32_16x16x32_bf16(b1, qf[k6], s1, 0, 0, 0);
            }
            __builtin_amdgcn_s_setprio(0);

            // scores for q=cc (log2 domain; scale folded into wq_b)
            float v0[4], v1[4];
            if (krow0 + 31 <= qmin) {
#pragma unroll
                for (int i = 0; i < 4; ++i) { v0[i] = s0[i]; v1[i] = s1[i]; }
            } else {
#pragma unroll
                for (int i = 0; i < 4; ++i) {
                    v0[i] = (krow0 + g * 4 + i) <= q_lane ? s0[i] : -1e30f;
                    v1[i] = (krow0 + 16 + g * 4 + i) <= q_lane ? s1[i] : -1e30f;
                }
            }
            float mt = fmaxf(fmaxf(fmaxf(v0[0], v0[1]), fmaxf(v0[2], v0[3])),
                             fmaxf(fmaxf(v1[0], v1[1]), fmaxf(v1[2], v1[3])));
            mt = fmaxf(mt, __shfl_xor(mt, 16));
            mt = fmaxf(mt, __shfl_xor(mt, 32));

            // T13 defer-rescale: wave-uniform skip when max grows < 6 (log2)
            if (!__all(mt <= m_r + 6.0f)) {
                float mn = fmaxf(m_r, mt);
                float alpha = exp2f(m_r - mn);
                m_r = mn;
                l_r *= alpha;
                float aB[4];
#pragma unroll
                for (int i = 0; i < 4; ++i) aB[i] = __shfl(alpha, g * 4 + i);
#pragma unroll
                for (int nt = 0; nt < 8; ++nt)
#pragma unroll
                    for (int i = 0; i < 4; ++i) accO[nt][i] *= aB[i];
            }

            float p0[4], p1[4], ps = 0.f;
#pragma unroll
            for (int i = 0; i < 4; ++i) {
                p0[i] = exp2f(v0[i] - m_r);   // masked lanes: exp2(-huge) = 0
                p1[i] = exp2f(v1[i] - m_r);
                ps += p0[i] + p1[i];
            }
            ps += __shfl_xor(ps, 16);
            ps += __shfl_xor(ps, 32);
            l_r += ps;

            // write P[q=cc][kv] to wave-private LDS (same-wave reuse only);
            // bf16 pack via HW cvt_pk (RNE, identical to f2bf on [0,1] data)
            {
                unsigned pk00, pk01, pk10, pk11;
                asm("v_cvt_pk_bf16_f32 %0, %1, %2" : "=v"(pk00) : "v"(p0[0]), "v"(p0[1]));
                asm("v_cvt_pk_bf16_f32 %0, %1, %2" : "=v"(pk01) : "v"(p0[2]), "v"(p0[3]));
                asm("v_cvt_pk_bf16_f32 %0, %1, %2" : "=v"(pk10) : "v"(p1[0]), "v"(p1[1]));
                asm("v_cvt_pk_bf16_f32 %0, %1, %2" : "=v"(pk11) : "v"(p1[2]), "v"(p1[3]));
                uint2 w0, w1;
                w0.x = pk00; w0.y = pk01;
                w1.x = pk10; w1.y = pk11;
                *(uint2*)&Pw[cc * 40 + g * 4] = w0;
                *(uint2*)&Pw[cc * 40 + 16 + g * 4] = w1;
            }

            short8 pf = *(const short8*)&Pw[cc * 40 + g * 8];
            __builtin_amdgcn_s_setprio(1);
#pragma unroll
            for (int nt = 0; nt < 8; ++nt) {
                short8 vr = *(const short8*)&Vc[(nt * 16 + cc) * 32 + g * 8];
                accO[nt] = __builtin_amdgcn_mfma_f32_16x16x32_bf16(pf, vr, accO[nt], 0, 0, 0);
            }
            __builtin_amdgcn_s_setprio(0);
        }
        cur ^= 1;
    }
#undef STAGE_KV

    // ---- emit unnormalized partial + (m,l) ----
    float mB[4], lB[4];
#pragma unroll
    for (int i = 0; i < 4; ++i) {
        int src = (g << 4) | (g * 4 + i);   // lane with cc == g*4+i (same g)
        mB[i] = __shfl(m_r, src);
        lB[i] = __shfl(l_r, src);
    }
    unsigned short* op = sp ? op1 : op0;
#pragma unroll
    for (int nt = 0; nt < 8; ++nt)
#pragma unroll
        for (int i = 0; i < 4; ++i)
            op[(size_t)pb * 8192 + (w * 16 + g * 4 + i) * 128 + nt * 16 + cc] =
                f2bf(accO[nt][i]);
    if (cc == 0) {
#pragma unroll
        for (int i = 0; i < 4; ++i) {
            size_t mi = ((size_t)(sp * 512 + pb) * 64 + w * 16 + g * 4 + i) * 2;
            mlp[mi + 0] = mB[i];
            mlp[mi + 1] = lB[i];
        }
    }
}

// ---------------------------------------------------------------------------
// merge_attn: combine the two kv-split partials per (h,qblk) -> ao bf16.
// grid 512 blocks x 256 threads; thread = (row = tid>>2, 32-col segment).
// ---------------------------------------------------------------------------
__global__ __launch_bounds__(256) void merge_attn(
    const unsigned short* __restrict__ op0, const unsigned short* __restrict__ op1,
    const float* __restrict__ mlp, unsigned short* __restrict__ ao)
{
    const int pb = blockIdx.x;           // h*32 + qblk
    const int h = pb >> 5, qblk = pb & 31;
    const int tid = threadIdx.x;
    const int row = tid >> 2, c0 = (tid & 3) * 32;

    const size_t mi0 = ((size_t)pb * 64 + row) * 2;
    const size_t mi1 = ((size_t)(512 + pb) * 64 + row) * 2;
    float m0 = mlp[mi0 + 0], l0 = mlp[mi0 + 1];
    float m1 = mlp[mi1 + 0], l1 = mlp[mi1 + 1];
    float mf = fmaxf(m0, m1);
    float e0 = exp2f(m0 - mf), e1 = exp2f(m1 - mf);
    float inv = 1.f / (l0 * e0 + l1 * e1);
    float w0 = e0 * inv, w1 = e1 * inv;

    const size_t pbase = (size_t)pb * 8192 + row * 128 + c0;
    unsigned short* dst = ao + (size_t)(qblk * 64 + row) * (NH_ * DV_) + h * DV_ + c0;
#pragma unroll
    for (int j = 0; j < 4; ++j) {
        short8 a = *(const short8*)&op0[pbase + j * 8];
        short8 b = *(const short8*)&op1[pbase + j * 8];
        short8 o;
#pragma unroll
        for (int k = 0; k < 8; ++k)
            o[k] = (short)f2bf(bf2f((unsigned short)a[k]) * w0 +
                               bf2f((unsigned short)b[k]) * w1);
        *(short8*)&dst[j * 8] = o;
    }
}

// ---------------------------------------------------------------------------
extern "C" void kernel_launch(void* const* d_in, const int* in_sizes, int n_in,
                              void* d_out, int out_size, void* d_ws, size_t ws_size,
                              hipStream_t stream)
{
    const float* hs    = (const float*)d_in[0];
    const float* cosp  = (const float*)d_in[1];
    const float* sinp  = (const float*)d_in[2];
    const float* wq_a  = (const float*)d_in[3];
    const float* q_ln  = (const float*)d_in[4];
    const float* wq_b  = (const float*)d_in[5];
    const float* wkv_a = (const float*)d_in[6];
    const float* kv_ln = (const float*)d_in[7];
    const float* wkv_b = (const float*)d_in[8];
    const float* wo    = (const float*)d_in[9];
    float* out = (float*)d_out;

    char* ws = (char*)d_ws;
    float*          qa     = (float*)(ws);                        // [2048][1536] f32 (dead after rms -> wbt2/kg)
    float*          ckv    = (float*)(ws + 12582912);             // [2048][576]  f32 (dead after prep_k -> mlp)
    unsigned short* q_bf   = (unsigned short*)(ws + 17301504);    // [2048][3072] bf16
    unsigned short* kvb    = (unsigned short*)(ws + 29884416);    // [2048][4096] bf16
    unsigned short* hs_bf  = (unsigned short*)(ws + 46661632);    // [2048][2048] bf16 (dead after fused gemm -> vtb)
    unsigned short* qa_bf  = (unsigned short*)(ws + 55050240);    // [2048][1536] bf16 (dead after q_b gemm -> op0)
    unsigned short* ckv_bf = (unsigned short*)(ws + 61341696);    // [2048][512]  bf16
    unsigned short* ao_bf  = (unsigned short*)(ws + 63438848);    // [2048][2048] bf16
    unsigned short* wt     = (unsigned short*)(ws + 71827456);    // [3072][1536] bf16 max (dead during flash -> op1)
    unsigned short* kg     = (unsigned short*)qa;                 // [16][2048][192] bf16
    unsigned short* vtb    = hs_bf;                               // [16*128][2048] bf16
    unsigned short* wbt2   = (unsigned short*)qa;                 // [4096][512] bf16 (wkv_b^T; qa dead, kg written later)

    // flash partials (alias dead regions during attention):
    unsigned short* op0 = qa_bf;                       // 512*8192 bf16 = 8.39 MB
    unsigned short* op1 = wt;                          // 512*8192 bf16 = 8.39 MB
    float*          mlp = ckv;                         // 2*512*64*2 f32 = 0.5 MB

    // scores scale * log2(e), folded into wq_b (q only feeds QK^T; RoPE linear)
    const float qscale = 0.07216878364870322f * 1.4426950408889634f;

    // hs -> bf16
    cast_bf16<<<(S_ * H_) / 1024, 256, 0, stream>>>(hs, hs_bf, S_ * H_);

    // fused q_a|kv_a projection: Bt = [wq_a^T (1536 rows) | wkv_a^T (576 rows)]
    transpose_cast<<<dim3(QLR_ / 32, H_ / 32), 256, 0, stream>>>(wq_a, wt, H_, QLR_, 1.f);
    transpose_cast<<<dim3(CKVW_ / 32, H_ / 32), 256, 0, stream>>>(
        wkv_a, wt + (size_t)QLR_ * H_, H_, CKVW_, 1.f);
    gemm_bf16_dual<<<dim3((QLR_ + CKVW_ + 127) / 128, S_ / 64), 256, 0, stream>>>(
        hs_bf, wt, qa, ckv, S_, QLR_ + CKVW_, H_, H_, QLR_, CKVW_);
    rmsnorm_bf16out<<<S_, 256, 0, stream>>>(qa, q_ln, qa_bf, QLR_, QLR_);
    rmsnorm_bf16out<<<S_, 256, 0, stream>>>(ckv, kv_ln, ckv_bf, KVLR_, CKVW_);

    // q_b + kv_b in ONE launch, 128x128 BK=32 tile (round-13):
    // grids 24x16=384 and 32x16=512 -> 896 blocks (~3.5/CU)
    transpose_cast<<<dim3(QW_ / 32, QLR_ / 32), 256, 0, stream>>>(wq_b, wt, QLR_, QW_, qscale);
    transpose_cast<<<dim3(KVW_ / 32, KVLR_ / 32), 256, 0, stream>>>(wkv_b, wbt2, KVLR_, KVW_, 1.f);
    gemm_bf16_pair<<<384 + 512, 256, 0, stream>>>(
        qa_bf, wt, q_bf, QW_, QLR_, QLR_, QW_, QW_ / 128, 384,
        ckv_bf, wbt2, kvb, KVW_, KVLR_, KVLR_, KVW_, KVW_ / 128, 512);
    rope_q_bf<<<(S_ * NH_ * 32) / 256, 256, 0, stream>>>(q_bf, cosp, sinp);

    // build kg (swizzled, rope fused; overwrites wbt2) and vt
    prep_k<<<S_, 256, 0, stream>>>(kvb, ckv, cosp, sinp, kg);
    transpose_v<<<dim3(4, 64, 16), 256, 0, stream>>>(kvb, vtb);

    // attention: fully-staged inner loop, 2-way block kv-split, 3 blocks/CU
    flash_attn7<<<1024, 256, 0, stream>>>(q_bf, kg, vtb, op0, op1, mlp);
    merge_attn<<<512, 256, 0, stream>>>(op0, op1, mlp, ao_bf);

    // output projection (wt reused AFTER merge has consumed op1)
    transpose_cast<<<dim3(H_ / 32, H_ / 32), 256, 0, stream>>>(wo, wt, H_, H_, 1.f);
    gemm_bf16_db<float, 128><<<dim3(H_ / 128, S_ / 64), 256, 0, stream>>>(
        ao_bf, wt, out, S_, H_, NH_ * DV_, NH_ * DV_, H_);
}